// Round 2
// baseline (17007.651 us; speedup 1.0000x reference)
//
#include <hip/hip_runtime.h>

// Problem constants (B=4, C=64, H=128, W=512)
#define HW_   65536        // H*W
#define CHW_  4194304      // C*H*W
#define OUTR_ 16777216     // B*C*H*W  (offset of out_r in d_out)
#define ROWU  36           // uint32 per LDS row: 64 bf16 (32 u32) + 4 u32 pad -> 144 B, 16B aligned

__device__ __forceinline__ unsigned b16rne(float f) {
  union { float f; unsigned u; } v; v.f = f;
  return (v.u + 0x7FFFu + ((v.u >> 16) & 1u)) >> 16;
}
__device__ __forceinline__ unsigned pack2(float a, float b) {
  return b16rne(a) | (b16rne(b) << 16);
}
__device__ __forceinline__ float bflo(unsigned u) {
  union { unsigned q; float f; } x; x.q = u << 16; return x.f;
}
__device__ __forceinline__ float bfhi(unsigned u) {
  union { unsigned q; float f; } x; x.q = u & 0xFFFF0000u; return x.f;
}

__device__ __forceinline__ void loadrow(float (&x)[64], const float* __restrict__ p,
                                        int base, int t) {
#pragma unroll
  for (int c = 0; c < 64; ++c) x[c] = p[base + c * HW_ + t];
}

__device__ __forceinline__ void layernorm(float (&x)[64], const float* __restrict__ w,
                                          const float* __restrict__ bb) {
  float s = 0.f;
#pragma unroll
  for (int c = 0; c < 64; ++c) s += x[c];
  float mu = s * 0.015625f;
  float v = 0.f;
#pragma unroll
  for (int c = 0; c < 64; ++c) { float d = x[c] - mu; v = fmaf(d, d, v); }
  float rs = rsqrtf(v * 0.015625f + 1e-6f);
#pragma unroll
  for (int c = 0; c < 64; ++c) x[c] = (x[c] - mu) * rs * w[c] + bb[c];
}

// y[o] = sum_c x[c] * W[o][c] + bias[o], packed bf16 pairs into dst (own LDS row)
__device__ __forceinline__ void proj_to_lds(const float (&x)[64], const float* __restrict__ W,
                                            const float* __restrict__ bias, unsigned* dst) {
  for (int o = 0; o < 64; o += 2) {           // o is wave-uniform -> weights via scalar path
    float a0 = bias[o], a1 = bias[o + 1];
#pragma unroll
    for (int c = 0; c < 64; ++c) {
      a0 = fmaf(x[c], W[o * 64 + c], a0);
      a1 = fmaf(x[c], W[(o + 1) * 64 + c], a1);
    }
    dst[o >> 1] = pack2(a0, a1);
  }
}

// Online-softmax attention: q (fp32 regs) vs 512 keys/vals in LDS (bf16 rows).
// O <- softmax(q . K^T * 0.125) @ Vals, normalized.
__device__ __forceinline__ void attention(const float (&q)[64],
                                          const unsigned* __restrict__ keys,
                                          const unsigned* __restrict__ vals,
                                          float (&O)[64]) {
  const float L2E = 1.44269504089f;
  float m = -INFINITY, l = 0.f;
#pragma unroll
  for (int c = 0; c < 64; ++c) O[c] = 0.f;

  for (int v0 = 0; v0 < 512; v0 += 8) {
    float s[8];
#pragma unroll
    for (int j = 0; j < 8; ++j) {
      const unsigned* row = keys + (v0 + j) * ROWU;
      float a = 0.f;
#pragma unroll
      for (int u = 0; u < 32; ++u) {
        unsigned w = row[u];
        a = fmaf(q[2 * u], bflo(w), a);
        a = fmaf(q[2 * u + 1], bfhi(w), a);
      }
      s[j] = a * 0.125f;   // * C^-0.5
    }
    float cm = s[0];
#pragma unroll
    for (int j = 1; j < 8; ++j) cm = fmaxf(cm, s[j]);
    float mn = fmaxf(m, cm);
    float corr = exp2f((m - mn) * L2E);
    l *= corr;
#pragma unroll
    for (int c = 0; c < 64; ++c) O[c] *= corr;
    m = mn;

    float p[8];
#pragma unroll
    for (int j = 0; j < 8; ++j) { p[j] = exp2f((s[j] - m) * L2E); l += p[j]; }

#pragma unroll
    for (int j = 0; j < 8; ++j) {
      const unsigned* row = vals + (v0 + j) * ROWU;
#pragma unroll
      for (int u = 0; u < 32; ++u) {
        unsigned w = row[u];
        O[2 * u]     = fmaf(p[j], bflo(w), O[2 * u]);
        O[2 * u + 1] = fmaf(p[j], bfhi(w), O[2 * u + 1]);
      }
    }
  }
  float inv = 1.0f / l;
#pragma unroll
  for (int c = 0; c < 64; ++c) O[c] *= inv;
}

// out[b,o,h,t] = xres[b,o,h,t] + gm[o] * ( sum_c O[c]*W[o][c] + bias[o] )
__device__ __forceinline__ void epilogue(const float (&O)[64], const float* __restrict__ W,
                                         const float* __restrict__ bias,
                                         const float* __restrict__ gm,
                                         const float* __restrict__ xres,
                                         float* __restrict__ outp, int base, int t) {
  for (int o = 0; o < 64; ++o) {
    float g = bias[o];
#pragma unroll
    for (int c = 0; c < 64; ++c) g = fmaf(O[c], W[o * 64 + c], g);
    int idx = base + o * HW_ + t;
    outp[idx] = xres[idx] + gm[o] * g;
  }
}

__global__ __launch_bounds__(512)
void scam_fused(const float* __restrict__ xl, const float* __restrict__ xr,
                const float* __restrict__ nlw, const float* __restrict__ nlb,
                const float* __restrict__ nrw, const float* __restrict__ nrb,
                const float* __restrict__ l1w, const float* __restrict__ l1b,
                const float* __restrict__ r1w, const float* __restrict__ r1b,
                const float* __restrict__ l2w, const float* __restrict__ l2b,
                const float* __restrict__ r2w, const float* __restrict__ r2b,
                const float* __restrict__ beta, const float* __restrict__ gamma,
                float* __restrict__ out) {
  __shared__ unsigned shA[512 * ROWU];   // 72 KiB
  __shared__ unsigned shB[512 * ROWU];   // 72 KiB
  const int t = threadIdx.x;             // pixel w (and v in pass 2)
  const int r = blockIdx.x;              // (b,h) row
  const int b = r >> 7, h = r & 127;
  const int base = b * CHW_ + h * 512;

  float x[64];
  float q[64];

  // ---- P0: Q_l -> shB (own row), then pull own Q_l into registers ----
  loadrow(x, xl, base, t);
  layernorm(x, nlw, nlb);
  proj_to_lds(x, l1w, l1b, shB + t * ROWU);
  // own-row RAW only; no cross-thread hazard yet
#pragma unroll
  for (int u = 0; u < 32; ++u) {
    unsigned w = shB[t * ROWU + u];
    q[2 * u] = bflo(w); q[2 * u + 1] = bfhi(w);
  }

  // ---- P1: raw x_r -> shB, Q_r -> shA (own rows) ----
  loadrow(x, xr, base, t);
#pragma unroll
  for (int u = 0; u < 32; ++u) shB[t * ROWU + u] = pack2(x[2 * u], x[2 * u + 1]);
  layernorm(x, nrw, nrb);
  proj_to_lds(x, r1w, r1b, shA + t * ROWU);
  __syncthreads();

  // ---- A1: F_r2l = Attn(Q_l, Q_r, x_r) ; out_l = x_l + beta * (O @ r2_w^T + r2_b) ----
  {
    float O[64];
    attention(q, shA, shB, O);
    epilogue(O, r2w, r2b, beta, xl, out, base, t);
  }
  __syncthreads();   // all A1 LDS reads done before P3 overwrites

  // ---- P3: pull own Q_r into regs, then raw x_l -> shB, Q_l -> shA ----
#pragma unroll
  for (int u = 0; u < 32; ++u) {
    unsigned w = shA[t * ROWU + u];
    q[2 * u] = bflo(w); q[2 * u + 1] = bfhi(w);
  }
  loadrow(x, xl, base, t);
#pragma unroll
  for (int u = 0; u < 32; ++u) shB[t * ROWU + u] = pack2(x[2 * u], x[2 * u + 1]);
  layernorm(x, nlw, nlb);
  proj_to_lds(x, l1w, l1b, shA + t * ROWU);
  __syncthreads();

  // ---- A2: F_l2r = Attn(Q_r, Q_l, x_l) ; out_r = x_r + gamma * (O @ l2_w^T + l2_b) ----
  {
    float O[64];
    attention(q, shA, shB, O);
    epilogue(O, l2w, l2b, gamma, xr, out + OUTR_, base, t);
  }
}

extern "C" void kernel_launch(void* const* d_in, const int* in_sizes, int n_in,
                              void* d_out, int out_size, void* d_ws, size_t ws_size,
                              hipStream_t stream) {
  (void)in_sizes; (void)n_in; (void)d_ws; (void)ws_size; (void)out_size;
  scam_fused<<<dim3(512), dim3(512), 0, stream>>>(
      (const float*)d_in[0],  (const float*)d_in[1],
      (const float*)d_in[2],  (const float*)d_in[3],
      (const float*)d_in[4],  (const float*)d_in[5],
      (const float*)d_in[6],  (const float*)d_in[7],
      (const float*)d_in[8],  (const float*)d_in[9],
      (const float*)d_in[10], (const float*)d_in[11],
      (const float*)d_in[12], (const float*)d_in[13],
      (const float*)d_in[14], (const float*)d_in[15],
      (float*)d_out);
}

// Round 3
// 731.454 us; speedup vs baseline: 23.2518x; 23.2518x over previous
//
#include <hip/hip_runtime.h>

#define HW_   65536        // H*W
#define CHW_  4194304      // C*H*W
#define OUTR_ 16777216     // offset of out_r in d_out (floats)

typedef __attribute__((ext_vector_type(4))) float    f32x4;
typedef __attribute__((ext_vector_type(8))) short    s16x8;
typedef __attribute__((ext_vector_type(4))) short    s16x4;
typedef __attribute__((ext_vector_type(4))) unsigned u32x4;
typedef __attribute__((ext_vector_type(2))) unsigned u32x2;

#define MFMA32(A,B,C) __builtin_amdgcn_mfma_f32_16x16x32_bf16((A),(B),(C),0,0,0)

#if __has_builtin(__builtin_amdgcn_mfma_f32_16x16x16bf16_1k)
#define MFMA16(A,B,C) __builtin_amdgcn_mfma_f32_16x16x16bf16_1k((A),(B),(C),0,0,0)
#else
__device__ __forceinline__ f32x4 mfma16_asm(s16x4 a, s16x4 b, f32x4 c){
  asm volatile("v_mfma_f32_16x16x16_bf16 %0, %1, %2, %0\n\ts_nop 7" : "+v"(c) : "v"(a), "v"(b));
  return c;
}
#define MFMA16(A,B,C) mfma16_asm((A),(B),(C))
#endif

#if __has_builtin(__builtin_amdgcn_exp2f)
#define EXP2(x) __builtin_amdgcn_exp2f(x)
#else
#define EXP2(x) exp2f(x)
#endif

#define QSCALE 0.18033688011112043f   // C^-0.5 * log2(e), folded into Q at extraction

__device__ __forceinline__ unsigned b16rne(float f) {
  union { float f; unsigned u; } v; v.f = f;
  return (v.u + 0x7FFFu + ((v.u >> 16) & 1u)) >> 16;
}
__device__ __forceinline__ unsigned pack2(float a, float b) {
  return b16rne(a) | (b16rne(b) << 16);
}
__device__ __forceinline__ float bflo(unsigned u) {
  union { unsigned q; float f; } x; x.q = u << 16; return x.f;
}
__device__ __forceinline__ float bfhi(unsigned u) {
  union { unsigned q; float f; } x; x.q = u & 0xFFFF0000u; return x.f;
}
__device__ __forceinline__ s16x8 as_s16x8(u32x4 u){ union{u32x4 a; s16x8 b;} x; x.a=u; return x.b; }
__device__ __forceinline__ s16x4 as_s16x4(u32x2 u){ union{u32x2 a; s16x4 b;} x; x.a=u; return x.b; }

// row-major [N][64]bf16 tile (128 B rows), guide-standard XOR swizzle
__device__ __forceinline__ int swz128(int row, int bir) { return row*128 + (bir ^ ((row&7)<<4)); }
// V^T tile [64][512]bf16 (1024 B rows), 6-bit XOR swizzle (16B-granular)
__device__ __forceinline__ int swzV(int c, int bir)    { return c*1024 + (bir ^ ((c&63)<<4)); }

__device__ __forceinline__ void loadrow(float (&x)[64], const float* __restrict__ p, int base, int t) {
#pragma unroll
  for (int c = 0; c < 64; ++c) x[c] = p[base + c*HW_ + t];
}

// LayerNorm over xv[64] then pack bf16 into buf row (swizzled)
__device__ __forceinline__ void ln_pack_store(const float (&xv)[64], const float* __restrict__ w,
                                              const float* __restrict__ bb, char* buf, int row) {
  float s = 0.f;
#pragma unroll
  for (int c = 0; c < 64; ++c) s += xv[c];
  float mu = s * 0.015625f;
  float v = 0.f;
#pragma unroll
  for (int c = 0; c < 64; ++c) { float d = xv[c]-mu; v = fmaf(d,d,v); }
  float rs = rsqrtf(v*0.015625f + 1e-6f);
#pragma unroll
  for (int i = 0; i < 8; ++i) {
    u32x4 u;
#pragma unroll
    for (int e = 0; e < 4; ++e) {
      int c0 = i*8 + e*2;
      float y0 = (xv[c0  ]-mu)*rs*w[c0  ] + bb[c0  ];
      float y1 = (xv[c0+1]-mu)*rs*w[c0+1] + bb[c0+1];
      u[e] = pack2(y0, y1);
    }
    *(u32x4*)(buf + swz128(row, i*16)) = u;
  }
}

// stage 64x64 fp32 weight matrix (row-major [out][in]) -> bf16 LDS, swizzled
__device__ __forceinline__ void stageW(const float* __restrict__ Wg, char* bufW, int t) {
  int row = t >> 3, c0 = (t & 7) * 8;
  f32x4 f0 = *(const f32x4*)(Wg + row*64 + c0);
  f32x4 f1 = *(const f32x4*)(Wg + row*64 + c0 + 4);
  u32x4 u = { pack2(f0[0],f0[1]), pack2(f0[2],f0[3]), pack2(f1[0],f1[1]), pack2(f1[2],f1[3]) };
  *(u32x4*)(bufW + swz128(row, c0*2)) = u;
}

// stage x (NCHW row) -> V^T [c][w] bf16 LDS (native layout is already [c][w]!)
__device__ __forceinline__ void stageV(const float* __restrict__ x, int base, char* bufV, int t) {
  int c = t >> 3, w0 = (t & 7) * 64;
#pragma unroll
  for (int i = 0; i < 8; ++i) {
    int w = w0 + i*8;
    f32x4 f0 = *(const f32x4*)(x + base + c*HW_ + w);
    f32x4 f1 = *(const f32x4*)(x + base + c*HW_ + w + 4);
    u32x4 u = { pack2(f0[0],f0[1]), pack2(f0[2],f0[3]), pack2(f1[0],f1[1]), pack2(f1[2],f1[3]) };
    *(u32x4*)(bufV + swzV(c, w*2)) = u;
  }
}

// [512x64] @ W^T + bias via MFMA; in/out row-major bf16 swizzled LDS tiles
__device__ __forceinline__ void proj64(const char* bufIn, const char* bufW, const float* biasS,
                                       char* bufOut, int wave, int lane) {
  int g = lane >> 4, q15 = lane & 15;
  u32x4 a[4][2], wb[4][2];
#pragma unroll
  for (int mt = 0; mt < 4; ++mt)
#pragma unroll
    for (int h = 0; h < 2; ++h)
      a[mt][h] = *(const u32x4*)(bufIn + swz128(wave*64 + mt*16 + q15, h*64 + g*16));
#pragma unroll
  for (int ot = 0; ot < 4; ++ot)
#pragma unroll
    for (int h = 0; h < 2; ++h)
      wb[ot][h] = *(const u32x4*)(bufW + swz128(ot*16 + q15, h*64 + g*16));
#pragma unroll
  for (int mt = 0; mt < 4; ++mt) {
#pragma unroll
    for (int ot = 0; ot < 4; ++ot) {
      f32x4 z = {0.f,0.f,0.f,0.f};
      f32x4 acc = MFMA32(as_s16x8(a[mt][0]), as_s16x8(wb[ot][0]), z);
      acc = MFMA32(as_s16x8(a[mt][1]), as_s16x8(wb[ot][1]), acc);
      float bv = biasS[ot*16 + q15];
#pragma unroll
      for (int rr = 0; rr < 4; ++rr)
        *(short*)(bufOut + swz128(wave*64 + mt*16 + 4*g + rr, 2*(ot*16 + q15))) =
            (short)b16rne(acc[rr] + bv);
    }
  }
}

// pull own 64 q-rows as B-fragments (pre-scaled by QSCALE)
__device__ __forceinline__ void extract_q(const char* bufQ, int wave, int lane, s16x8 (&qf)[4][2]) {
  int g = lane >> 4, q15 = lane & 15;
#pragma unroll
  for (int qt = 0; qt < 4; ++qt)
#pragma unroll
    for (int h = 0; h < 2; ++h) {
      u32x4 u = *(const u32x4*)(bufQ + swz128(wave*64 + qt*16 + q15, h*64 + g*16));
#pragma unroll
      for (int e = 0; e < 4; ++e)
        u[e] = pack2(bflo(u[e])*QSCALE, bfhi(u[e])*QSCALE);
      qf[qt][h] = as_s16x8(u);
    }
}

// flash attention: K in bufK ([512][64] swz), V^T in bufV, Q-frags in regs
__device__ __forceinline__ void flash_pass(const char* bufK, const char* bufV, const s16x8 (&qf)[4][2],
                                           f32x4 (&O)[4][4], float (&mref)[4], float (&lsum)[4], int lane) {
  int g = lane >> 4, q15 = lane & 15;
#pragma unroll
  for (int qt = 0; qt < 4; ++qt) {
    mref[qt] = -__builtin_inff(); lsum[qt] = 0.f;
#pragma unroll
    for (int ct = 0; ct < 4; ++ct) { f32x4 z = {0.f,0.f,0.f,0.f}; O[qt][ct] = z; }
  }
#pragma unroll 1
  for (int ch = 0; ch < 16; ++ch) {
    int kbase = ch * 32;
    u32x4 ka[2][2];
#pragma unroll
    for (int kb = 0; kb < 2; ++kb)
#pragma unroll
      for (int h = 0; h < 2; ++h)
        ka[kb][h] = *(const u32x4*)(bufK + swz128(kbase + kb*16 + q15, h*64 + g*16));
    u32x2 vb[4][2];
#pragma unroll
    for (int ct = 0; ct < 4; ++ct) {
      int c = ct*16 + q15;
#pragma unroll
      for (int kb = 0; kb < 2; ++kb)
        vb[ct][kb] = *(const u32x2*)(bufV + swzV(c, (kbase + kb*16 + 4*g)*2));
    }
#pragma unroll
    for (int qt = 0; qt < 4; ++qt) {
      f32x4 z = {0.f,0.f,0.f,0.f};
      f32x4 a0 = MFMA32(as_s16x8(ka[0][0]), qf[qt][0], z);
      a0 = MFMA32(as_s16x8(ka[0][1]), qf[qt][1], a0);
      f32x4 a1 = MFMA32(as_s16x8(ka[1][0]), qf[qt][0], z);
      a1 = MFMA32(as_s16x8(ka[1][1]), qf[qt][1], a1);
      // chunk max for this lane's q (keys spread over 4 lanes: xor16, xor32)
      float cm = fmaxf(fmaxf(fmaxf(a0[0],a0[1]), fmaxf(a0[2],a0[3])),
                       fmaxf(fmaxf(a1[0],a1[1]), fmaxf(a1[2],a1[3])));
      cm = fmaxf(cm, __shfl_xor(cm, 16));
      cm = fmaxf(cm, __shfl_xor(cm, 32));
      if (__any(cm > mref[qt] + 8.f)) {       // deferred rescale (log2 domain)
        float nm = fmaxf(mref[qt], cm);
        float corr = EXP2(mref[qt] - nm);
        lsum[qt] *= corr; mref[qt] = nm;
#pragma unroll
        for (int rr = 0; rr < 4; ++rr) {
          float cr = __shfl(corr, 4*g + rr);
#pragma unroll
          for (int ct = 0; ct < 4; ++ct) O[qt][ct][rr] *= cr;
        }
      }
      float p[8], sm = 0.f;
#pragma unroll
      for (int j = 0; j < 4; ++j) { p[j]   = EXP2(a0[j] - mref[qt]); sm += p[j]; }
#pragma unroll
      for (int j = 0; j < 4; ++j) { p[4+j] = EXP2(a1[j] - mref[qt]); sm += p[4+j]; }
      float s1 = sm + __shfl_xor(sm, 16);
      float s2 = s1 + __shfl_xor(s1, 32);
      lsum[qt] += s2;
      u32x2 pa0 = { pack2(p[0],p[1]), pack2(p[2],p[3]) };
      u32x2 pa1 = { pack2(p[4],p[5]), pack2(p[6],p[7]) };
#pragma unroll
      for (int ct = 0; ct < 4; ++ct) {
        O[qt][ct] = MFMA16(as_s16x4(pa0), as_s16x4(vb[ct][0]), O[qt][ct]);
        O[qt][ct] = MFMA16(as_s16x4(pa1), as_s16x4(vb[ct][1]), O[qt][ct]);
      }
    }
  }
}

// normalize by 1/l and store O bf16 -> [512][64] swizzled tile
__device__ __forceinline__ void write_O(char* buf, const f32x4 (&O)[4][4], const float (&lsum)[4],
                                        int wave, int lane) {
  int g = lane >> 4, q15 = lane & 15;
#pragma unroll
  for (int qt = 0; qt < 4; ++qt) {
    float inv = 1.f / lsum[qt];
    float invr[4];
#pragma unroll
    for (int rr = 0; rr < 4; ++rr) invr[rr] = __shfl(inv, 4*g + rr);
#pragma unroll
    for (int ct = 0; ct < 4; ++ct)
#pragma unroll
      for (int rr = 0; rr < 4; ++rr)
        *(short*)(buf + swz128(wave*64 + qt*16 + 4*g + rr, 2*(ct*16 + q15))) =
            (short)b16rne(O[qt][ct][rr] * invr[rr]);
  }
}

// epilogue: out = xres + coef*G (coalesced per-thread row); optionally LN(xres) -> bufLN
template <bool DO_LN>
__device__ __forceinline__ void epilogue_row(const char* bufG, const float* __restrict__ xres,
                                             const float* coefS, float* __restrict__ outp,
                                             int base, int t,
                                             const float* lnw, const float* lnb, char* bufLN) {
  u32x4 gv[8];
#pragma unroll
  for (int i = 0; i < 8; ++i) gv[i] = *(const u32x4*)(bufG + swz128(t, i*16));
  float xv[64];
#pragma unroll
  for (int o = 0; o < 64; ++o) {
    unsigned w = gv[o >> 3][(o >> 1) & 3];
    float gval = (o & 1) ? bfhi(w) : bflo(w);
    float xr = xres[base + o*HW_ + t];
    xv[o] = xr;
    outp[base + o*HW_ + t] = xr + coefS[o] * gval;
  }
  if (DO_LN) ln_pack_store(xv, lnw, lnb, bufLN, t);
}

__global__ __launch_bounds__(512, 2)
void scam_mfma(const float* __restrict__ xl, const float* __restrict__ xr,
               const float* __restrict__ nlw, const float* __restrict__ nlb,
               const float* __restrict__ nrw, const float* __restrict__ nrb,
               const float* __restrict__ l1w, const float* __restrict__ l1b,
               const float* __restrict__ r1w, const float* __restrict__ r1b,
               const float* __restrict__ l2w, const float* __restrict__ l2b,
               const float* __restrict__ r2w, const float* __restrict__ r2b,
               const float* __restrict__ beta, const float* __restrict__ gamma,
               float* __restrict__ out) {
  __shared__ __align__(16) char bufA[65536];
  __shared__ __align__(16) char bufB[65536];
  __shared__ __align__(16) char bufW[8192];
  __shared__ float cst[10][64];   // 0:nlw 1:nlb 2:nrw 3:nrb 4:b1l 5:b1r 6:b2l 7:b2r 8:beta 9:gamma

  const int t = threadIdx.x, lane = t & 63, wave = t >> 6;
  const int r = blockIdx.x, b = r >> 7, h = r & 127;
  const int base = b*CHW_ + h*512;

  if (t < 64) {
    cst[0][t] = nlw[t];  cst[1][t] = nlb[t];  cst[2][t] = nrw[t]; cst[3][t] = nrb[t];
    cst[4][t] = l1b[t];  cst[5][t] = r1b[t];  cst[6][t] = l2b[t]; cst[7][t] = r2b[t];
    cst[8][t] = beta[t]; cst[9][t] = gamma[t];
  }
  { float xv[64]; loadrow(xv, xl, base, t); ln_pack_store(xv, cst[0]+0*0, cst[1], bufA, t); }
  // NOTE: cst written by t<64 above; LN uses cst[0..1] -> need them visible. Stage W first, then sync, then LN?
  // Safe ordering: W staged here too, then barrier, then LN in next phase would cost a pass.
  // Instead: LN weights are also available from global (broadcast) -- but keep it simple:
  __syncthreads();
  // Re-do LN of x_l with guaranteed-visible cst (cheap; x_l row is L1-hot):
  { float xv[64]; loadrow(xv, xl, base, t); ln_pack_store(xv, cst[0], cst[1], bufA, t); }
  stageW(l1w, bufW, t);
  __syncthreads();
  // P1: Q_l = LN(x_l) @ W1l^T + b1l -> bufB
  proj64(bufA, bufW, cst[4], bufB, wave, lane);
  __syncthreads();
  // P2: extract Q_l B-frags; LN(x_r) -> bufA; stage W1r
  s16x8 qfL[4][2];
  extract_q(bufB, wave, lane, qfL);
  { float xv[64]; loadrow(xv, xr, base, t); ln_pack_store(xv, cst[2], cst[3], bufA, t); }
  stageW(r1w, bufW, t);
  __syncthreads();
  // P3: Q_r -> bufB (overwrites Q_l; qfL saved in regs)
  proj64(bufA, bufW, cst[5], bufB, wave, lane);
  __syncthreads();
  // P4: extract Q_r B-frags (for A2); V^T = x_r -> bufA; stage W2r
  s16x8 qfR[4][2];
  extract_q(bufB, wave, lane, qfR);
  stageV(xr, base, bufA, t);
  stageW(r2w, bufW, t);
  __syncthreads();
  // A1: F_r2l = Attn(Q_l, Q_r, x_r)
  f32x4 O[4][4]; float mref[4], lsum[4];
  flash_pass(bufB, bufA, qfL, O, mref, lsum, lane);
  __syncthreads();
  write_O(bufB, O, lsum, wave, lane);     // P5: O1 -> bufB (Q_r dead)
  __syncthreads();
  proj64(bufB, bufW, cst[7], bufA, wave, lane);   // E1a: G1 = O1@W2r^T + b2r -> bufA
  __syncthreads();
  // E1b: out_l = x_l + beta*G1 ; LN(x_l) -> bufA ; stage W1l
  epilogue_row<true>(bufA, xl, cst[8], out, base, t, cst[0], cst[1], bufA);
  stageW(l1w, bufW, t);
  __syncthreads();
  proj64(bufA, bufW, cst[4], bufB, wave, lane);   // P7: Q_l again -> bufB
  __syncthreads();
  stageV(xl, base, bufA, t);                       // P8: V^T = x_l -> bufA
  stageW(l2w, bufW, t);
  __syncthreads();
  // A2: F_l2r = Attn(Q_r, Q_l, x_l)
  flash_pass(bufB, bufA, qfR, O, mref, lsum, lane);
  __syncthreads();
  write_O(bufB, O, lsum, wave, lane);     // P9: O2 -> bufB
  __syncthreads();
  proj64(bufB, bufW, cst[6], bufA, wave, lane);   // E2a: G2 = O2@W2l^T + b2l -> bufA
  __syncthreads();
  epilogue_row<false>(bufA, xr, cst[9], out + OUTR_, base, t, cst[0], cst[1], bufA);
}

extern "C" void kernel_launch(void* const* d_in, const int* in_sizes, int n_in,
                              void* d_out, int out_size, void* d_ws, size_t ws_size,
                              hipStream_t stream) {
  (void)in_sizes; (void)n_in; (void)d_ws; (void)ws_size; (void)out_size;
  scam_mfma<<<dim3(512), dim3(512), 0, stream>>>(
      (const float*)d_in[0],  (const float*)d_in[1],
      (const float*)d_in[2],  (const float*)d_in[3],
      (const float*)d_in[4],  (const float*)d_in[5],
      (const float*)d_in[6],  (const float*)d_in[7],
      (const float*)d_in[8],  (const float*)d_in[9],
      (const float*)d_in[10], (const float*)d_in[11],
      (const float*)d_in[12], (const float*)d_in[13],
      (const float*)d_in[14], (const float*)d_in[15],
      (float*)d_out);
}

// Round 4
// 623.283 us; speedup vs baseline: 27.2872x; 1.1736x over previous
//
#include <hip/hip_runtime.h>

#define HW_   65536        // H*W
#define CHW_  4194304      // C*H*W
#define OUTR_ 16777216     // offset of out_r in d_out (floats)

typedef __attribute__((ext_vector_type(4))) float    f32x4;
typedef __attribute__((ext_vector_type(8))) short    s16x8;
typedef __attribute__((ext_vector_type(4))) short    s16x4;
typedef __attribute__((ext_vector_type(4))) unsigned u32x4;
typedef __attribute__((ext_vector_type(2))) unsigned u32x2;

#define MFMA32(A,B,C) __builtin_amdgcn_mfma_f32_16x16x32_bf16((A),(B),(C),0,0,0)

#if __has_builtin(__builtin_amdgcn_mfma_f32_16x16x16bf16_1k)
#define MFMA16(A,B,C) __builtin_amdgcn_mfma_f32_16x16x16bf16_1k((A),(B),(C),0,0,0)
#else
__device__ __forceinline__ f32x4 mfma16_asm(s16x4 a, s16x4 b, f32x4 c){
  asm volatile("v_mfma_f32_16x16x16_bf16 %0, %1, %2, %0\n\ts_nop 7" : "+v"(c) : "v"(a), "v"(b));
  return c;
}
#define MFMA16(A,B,C) mfma16_asm((A),(B),(C))
#endif

#define EXP2(x) exp2f(x)
#define QSCALE 0.18033688011112043f   // C^-0.5 * log2(e), folded into Q at extraction

__device__ __forceinline__ unsigned b16rne(float f) {
  union { float f; unsigned u; } v; v.f = f;
  return (v.u + 0x7FFFu + ((v.u >> 16) & 1u)) >> 16;
}
__device__ __forceinline__ unsigned pack2(float a, float b) {
  return b16rne(a) | (b16rne(b) << 16);
}
__device__ __forceinline__ float bflo(unsigned u) {
  union { unsigned q; float f; } x; x.q = u << 16; return x.f;
}
__device__ __forceinline__ float bfhi(unsigned u) {
  union { unsigned q; float f; } x; x.q = u & 0xFFFF0000u; return x.f;
}
__device__ __forceinline__ s16x8 as_s16x8(u32x4 u){ union{u32x4 a; s16x8 b;} x; x.a=u; return x.b; }
__device__ __forceinline__ s16x4 as_s16x4(u32x2 u){ union{u32x2 a; s16x4 b;} x; x.a=u; return x.b; }

// row-major [N][64]bf16 tile (128 B rows), XOR swizzle (G4)
__device__ __forceinline__ int swz128(int row, int bir) { return row*128 + (bir ^ ((row&7)<<4)); }
// V^T tile [64][512]bf16 (1024 B rows), 6-bit XOR swizzle
__device__ __forceinline__ int swzV(int c, int bir)    { return c*1024 + (bir ^ ((c&63)<<4)); }

__device__ __forceinline__ void loadrow(float (&x)[64], const float* __restrict__ p, int base, int t) {
#pragma unroll
  for (int c = 0; c < 64; ++c) x[c] = p[base + c*HW_ + t];
}

// LayerNorm over xv[64] then pack bf16 into buf row (swizzled); w/bb read via scalar cache
__device__ __forceinline__ void ln_pack_store(const float (&xv)[64], const float* __restrict__ w,
                                              const float* __restrict__ bb, char* buf, int row) {
  float s = 0.f;
#pragma unroll
  for (int c = 0; c < 64; ++c) s += xv[c];
  float mu = s * 0.015625f;
  float v = 0.f;
#pragma unroll
  for (int c = 0; c < 64; ++c) { float d = xv[c]-mu; v = fmaf(d,d,v); }
  float rs = rsqrtf(v*0.015625f + 1e-6f);
#pragma unroll
  for (int i = 0; i < 8; ++i) {
    u32x4 u;
#pragma unroll
    for (int e = 0; e < 4; ++e) {
      int c0 = i*8 + e*2;
      float y0 = (xv[c0  ]-mu)*rs*w[c0  ] + bb[c0  ];
      float y1 = (xv[c0+1]-mu)*rs*w[c0+1] + bb[c0+1];
      u[e] = pack2(y0, y1);
    }
    *(u32x4*)(buf + swz128(row, i*16)) = u;
  }
}

// stage 64x64 fp32 weight matrix (row-major [out][in]) -> bf16 LDS, swizzled
__device__ __forceinline__ void stageW(const float* __restrict__ Wg, char* bufW, int t) {
  int row = t >> 3, c0 = (t & 7) * 8;
  f32x4 f0 = *(const f32x4*)(Wg + row*64 + c0);
  f32x4 f1 = *(const f32x4*)(Wg + row*64 + c0 + 4);
  u32x4 u = { pack2(f0[0],f0[1]), pack2(f0[2],f0[3]), pack2(f1[0],f1[1]), pack2(f1[2],f1[3]) };
  *(u32x4*)(bufW + swz128(row, c0*2)) = u;
}

// stage x (NCHW row) -> V^T [c][w] bf16 LDS (native layout is already [c][w])
__device__ __forceinline__ void stageV(const float* __restrict__ x, int base, char* bufV, int t) {
  int c = t >> 3, w0 = (t & 7) * 64;
#pragma unroll
  for (int i = 0; i < 8; ++i) {
    int w = w0 + i*8;
    f32x4 f0 = *(const f32x4*)(x + base + c*HW_ + w);
    f32x4 f1 = *(const f32x4*)(x + base + c*HW_ + w + 4);
    u32x4 u = { pack2(f0[0],f0[1]), pack2(f0[2],f0[3]), pack2(f1[0],f1[1]), pack2(f1[2],f1[3]) };
    *(u32x4*)(bufV + swzV(c, w*2)) = u;
  }
}

// [512x64] @ W^T + bias via MFMA; in/out row-major bf16 swizzled LDS tiles
__device__ __forceinline__ void proj64(const char* bufIn, const char* bufW,
                                       const float* __restrict__ biasG,
                                       char* bufOut, int wave, int lane) {
  int g = lane >> 4, q15 = lane & 15;
  u32x4 a[4][2], wb[4][2];
#pragma unroll
  for (int mt = 0; mt < 4; ++mt)
#pragma unroll
    for (int h = 0; h < 2; ++h)
      a[mt][h] = *(const u32x4*)(bufIn + swz128(wave*64 + mt*16 + q15, h*64 + g*16));
#pragma unroll
  for (int ot = 0; ot < 4; ++ot)
#pragma unroll
    for (int h = 0; h < 2; ++h)
      wb[ot][h] = *(const u32x4*)(bufW + swz128(ot*16 + q15, h*64 + g*16));
#pragma unroll
  for (int mt = 0; mt < 4; ++mt) {
#pragma unroll
    for (int ot = 0; ot < 4; ++ot) {
      f32x4 z = {0.f,0.f,0.f,0.f};
      f32x4 acc = MFMA32(as_s16x8(a[mt][0]), as_s16x8(wb[ot][0]), z);
      acc = MFMA32(as_s16x8(a[mt][1]), as_s16x8(wb[ot][1]), acc);
      float bv = biasG[ot*16 + q15];
#pragma unroll
      for (int rr = 0; rr < 4; ++rr)
        *(short*)(bufOut + swz128(wave*64 + mt*16 + 4*g + rr, 2*(ot*16 + q15))) =
            (short)b16rne(acc[rr] + bv);
    }
  }
}

// pull own 64 q-rows as B-fragments (pre-scaled by QSCALE)
__device__ __forceinline__ void extract_q(const char* bufQ, int wave, int lane, s16x8 (&qf)[4][2]) {
  int g = lane >> 4, q15 = lane & 15;
#pragma unroll
  for (int qt = 0; qt < 4; ++qt)
#pragma unroll
    for (int h = 0; h < 2; ++h) {
      u32x4 u = *(const u32x4*)(bufQ + swz128(wave*64 + qt*16 + q15, h*64 + g*16));
#pragma unroll
      for (int e = 0; e < 4; ++e)
        u[e] = pack2(bflo(u[e])*QSCALE, bfhi(u[e])*QSCALE);
      qf[qt][h] = as_s16x8(u);
    }
}

// flash attention: K in bufK ([512][64] swz), V^T in bufV, Q-frags in regs
__device__ __forceinline__ void flash_pass(const char* bufK, const char* bufV, const s16x8 (&qf)[4][2],
                                           f32x4 (&O)[4][4], float (&lsum)[4], int lane) {
  int g = lane >> 4, q15 = lane & 15;
  float mref[4];
#pragma unroll
  for (int qt = 0; qt < 4; ++qt) {
    mref[qt] = -__builtin_inff(); lsum[qt] = 0.f;
#pragma unroll
    for (int ct = 0; ct < 4; ++ct) { f32x4 z = {0.f,0.f,0.f,0.f}; O[qt][ct] = z; }
  }
#pragma unroll 1
  for (int ch = 0; ch < 16; ++ch) {
    int kbase = ch * 32;
    u32x4 ka[2][2];
#pragma unroll
    for (int kb = 0; kb < 2; ++kb)
#pragma unroll
      for (int h = 0; h < 2; ++h)
        ka[kb][h] = *(const u32x4*)(bufK + swz128(kbase + kb*16 + q15, h*64 + g*16));
    u32x2 vb[4][2];
#pragma unroll
    for (int ct = 0; ct < 4; ++ct) {
      int c = ct*16 + q15;
#pragma unroll
      for (int kb = 0; kb < 2; ++kb)
        vb[ct][kb] = *(const u32x2*)(bufV + swzV(c, (kbase + kb*16 + 4*g)*2));
    }
#pragma unroll
    for (int qt = 0; qt < 4; ++qt) {
      f32x4 z = {0.f,0.f,0.f,0.f};
      f32x4 a0 = MFMA32(as_s16x8(ka[0][0]), qf[qt][0], z);
      a0 = MFMA32(as_s16x8(ka[0][1]), qf[qt][1], a0);
      f32x4 a1 = MFMA32(as_s16x8(ka[1][0]), qf[qt][0], z);
      a1 = MFMA32(as_s16x8(ka[1][1]), qf[qt][1], a1);
      float cm = fmaxf(fmaxf(fmaxf(a0[0],a0[1]), fmaxf(a0[2],a0[3])),
                       fmaxf(fmaxf(a1[0],a1[1]), fmaxf(a1[2],a1[3])));
      cm = fmaxf(cm, __shfl_xor(cm, 16));
      cm = fmaxf(cm, __shfl_xor(cm, 32));
      if (__any(cm > mref[qt] + 8.f)) {       // deferred rescale (T13, log2 domain)
        float nm = fmaxf(mref[qt], cm);
        float corr = EXP2(mref[qt] - nm);
        lsum[qt] *= corr; mref[qt] = nm;
#pragma unroll
        for (int rr = 0; rr < 4; ++rr) {
          float cr = __shfl(corr, 4*g + rr);
#pragma unroll
          for (int ct = 0; ct < 4; ++ct) O[qt][ct][rr] *= cr;
        }
      }
      float p[8], sm = 0.f;
#pragma unroll
      for (int j = 0; j < 4; ++j) { p[j]   = EXP2(a0[j] - mref[qt]); sm += p[j]; }
#pragma unroll
      for (int j = 0; j < 4; ++j) { p[4+j] = EXP2(a1[j] - mref[qt]); sm += p[4+j]; }
      float s1 = sm + __shfl_xor(sm, 16);
      float s2 = s1 + __shfl_xor(s1, 32);
      lsum[qt] += s2;
      u32x2 pa0 = { pack2(p[0],p[1]), pack2(p[2],p[3]) };
      u32x2 pa1 = { pack2(p[4],p[5]), pack2(p[6],p[7]) };
#pragma unroll
      for (int ct = 0; ct < 4; ++ct) {
        O[qt][ct] = MFMA16(as_s16x4(pa0), as_s16x4(vb[ct][0]), O[qt][ct]);
        O[qt][ct] = MFMA16(as_s16x4(pa1), as_s16x4(vb[ct][1]), O[qt][ct]);
      }
    }
  }
}

// normalize by 1/l and store O bf16 -> [512][64] swizzled tile
__device__ __forceinline__ void write_O(char* buf, const f32x4 (&O)[4][4], const float (&lsum)[4],
                                        int wave, int lane) {
  int g = lane >> 4, q15 = lane & 15;
#pragma unroll
  for (int qt = 0; qt < 4; ++qt) {
    float inv = 1.f / lsum[qt];
    float invr[4];
#pragma unroll
    for (int rr = 0; rr < 4; ++rr) invr[rr] = __shfl(inv, 4*g + rr);
#pragma unroll
    for (int ct = 0; ct < 4; ++ct)
#pragma unroll
      for (int rr = 0; rr < 4; ++rr)
        *(short*)(buf + swz128(wave*64 + qt*16 + 4*g + rr, 2*(ct*16 + q15))) =
            (short)b16rne(O[qt][ct][rr] * invr[rr]);
  }
}

// out = xres + coef*G, chunked (low register pressure); coef via scalar cache
__device__ __forceinline__ void epilogue_row(const char* bufG, const float* __restrict__ xres,
                                             const float* __restrict__ coef,
                                             float* __restrict__ outp, int base, int t) {
#pragma unroll
  for (int i = 0; i < 8; ++i) {
    u32x4 gvv = *(const u32x4*)(bufG + swz128(t, i*16));
#pragma unroll
    for (int e = 0; e < 4; ++e) {
      int o = i*8 + e*2;
      outp[base + o*HW_ + t]     = xres[base + o*HW_ + t]     + coef[o]   * bflo(gvv[e]);
      outp[base + (o+1)*HW_ + t] = xres[base + (o+1)*HW_ + t] + coef[o+1] * bfhi(gvv[e]);
    }
  }
}

__global__ __launch_bounds__(512)
void scam_mfma(const float* __restrict__ xl, const float* __restrict__ xr,
               const float* __restrict__ nlw, const float* __restrict__ nlb,
               const float* __restrict__ nrw, const float* __restrict__ nrb,
               const float* __restrict__ l1w, const float* __restrict__ l1b,
               const float* __restrict__ r1w, const float* __restrict__ r1b,
               const float* __restrict__ l2w, const float* __restrict__ l2b,
               const float* __restrict__ r2w, const float* __restrict__ r2b,
               const float* __restrict__ beta, const float* __restrict__ gamma,
               float* __restrict__ out) {
  __shared__ __align__(16) char bufA[65536];
  __shared__ __align__(16) char bufB[65536];
  __shared__ __align__(16) char bufW[8192];

  const int t = threadIdx.x, lane = t & 63, wave = t >> 6;
  const int r = blockIdx.x, b = r >> 7, h = r & 127;
  const int base = b*CHW_ + h*512;

  // P0: LN(x_l) -> A ; W1l -> W
  { float xv[64]; loadrow(xv, xl, base, t); ln_pack_store(xv, nlw, nlb, bufA, t); }
  stageW(l1w, bufW, t);
  __syncthreads();
  // P1: Q_l = LN(x_l)@W1l^T + b1l -> B
  proj64(bufA, bufW, l1b, bufB, wave, lane);
  __syncthreads();
  // P2: qfL <- B ; LN(x_r) -> A ; W1r -> W
  s16x8 qfL[4][2];
  extract_q(bufB, wave, lane, qfL);
  { float xv[64]; loadrow(xv, xr, base, t); ln_pack_store(xv, nrw, nrb, bufA, t); }
  stageW(r1w, bufW, t);
  __syncthreads();
  // P3: Q_r -> B  (qfL lives in regs)
  proj64(bufA, bufW, r1b, bufB, wave, lane);
  __syncthreads();
  // P4: V^T = x_r -> A ; W2r -> W
  stageV(xr, base, bufA, t);
  stageW(r2w, bufW, t);
  __syncthreads();
  // A1: F_r2l = Attn(Q_l, Q_r, x_r)
  f32x4 O[4][4]; float lsum[4];
  flash_pass(bufB, bufA, qfL, O, lsum, lane);
  // Q_r tile (B) is still resident -- extract qfR only now (keeps A1 pressure low)
  s16x8 qfR[4][2];
  extract_q(bufB, wave, lane, qfR);
  __syncthreads();
  // P5: O1 -> A (V dead)
  write_O(bufA, O, lsum, wave, lane);
  __syncthreads();
  // E1a: G1 = O1@W2r^T + b2r -> B
  proj64(bufA, bufW, r2b, bufB, wave, lane);
  __syncthreads();
  // E1b: out_l = x_l + beta*G1 ; then LN(x_l) -> A ; W1l -> W
  epilogue_row(bufB, xl, beta, out, base, t);
  { float xv[64]; loadrow(xv, xl, base, t); ln_pack_store(xv, nlw, nlb, bufA, t); }
  stageW(l1w, bufW, t);
  __syncthreads();
  // P7: Q_l -> B
  proj64(bufA, bufW, l1b, bufB, wave, lane);
  __syncthreads();
  // P8: V^T = x_l -> A ; W2l -> W
  stageV(xl, base, bufA, t);
  stageW(l2w, bufW, t);
  __syncthreads();
  // A2: F_l2r = Attn(Q_r, Q_l, x_l)
  flash_pass(bufB, bufA, qfR, O, lsum, lane);
  __syncthreads();
  // P9: O2 -> A
  write_O(bufA, O, lsum, wave, lane);
  __syncthreads();
  // E2a: G2 = O2@W2l^T + b2l -> B
  proj64(bufA, bufW, l2b, bufB, wave, lane);
  __syncthreads();
  // E2b: out_r = x_r + gamma*G2
  epilogue_row(bufB, xr, gamma, out + OUTR_, base, t);
}

extern "C" void kernel_launch(void* const* d_in, const int* in_sizes, int n_in,
                              void* d_out, int out_size, void* d_ws, size_t ws_size,
                              hipStream_t stream) {
  (void)in_sizes; (void)n_in; (void)d_ws; (void)ws_size; (void)out_size;
  scam_mfma<<<dim3(512), dim3(512), 0, stream>>>(
      (const float*)d_in[0],  (const float*)d_in[1],
      (const float*)d_in[2],  (const float*)d_in[3],
      (const float*)d_in[4],  (const float*)d_in[5],
      (const float*)d_in[6],  (const float*)d_in[7],
      (const float*)d_in[8],  (const float*)d_in[9],
      (const float*)d_in[10], (const float*)d_in[11],
      (const float*)d_in[12], (const float*)d_in[13],
      (const float*)d_in[14], (const float*)d_in[15],
      (float*)d_out);
}

// Round 5
// 614.507 us; speedup vs baseline: 27.6769x; 1.0143x over previous
//
#include <hip/hip_runtime.h>

#define HW_   65536        // H*W
#define CHW_  4194304      // C*H*W
#define OUTR_ 16777216     // offset of out_r in d_out (floats)

typedef __attribute__((ext_vector_type(4))) float    f32x4;
typedef __attribute__((ext_vector_type(8))) short    s16x8;
typedef __attribute__((ext_vector_type(4))) short    s16x4;
typedef __attribute__((ext_vector_type(4))) unsigned u32x4;
typedef __attribute__((ext_vector_type(2))) unsigned u32x2;

#define MFMA32(A,B,C) __builtin_amdgcn_mfma_f32_16x16x32_bf16((A),(B),(C),0,0,0)

#if __has_builtin(__builtin_amdgcn_mfma_f32_16x16x16bf16_1k)
#define MFMA16(A,B,C) __builtin_amdgcn_mfma_f32_16x16x16bf16_1k((A),(B),(C),0,0,0)
#else
__device__ __forceinline__ f32x4 mfma16_asm(s16x4 a, s16x4 b, f32x4 c){
  asm volatile("v_mfma_f32_16x16x16_bf16 %0, %1, %2, %0\n\ts_nop 7" : "+v"(c) : "v"(a), "v"(b));
  return c;
}
#define MFMA16(A,B,C) mfma16_asm((A),(B),(C))
#endif

#define EXP2(x) exp2f(x)
#define QSCALE 0.18033688011112043f   // C^-0.5 * log2(e), folded into Q at extraction

__device__ __forceinline__ unsigned b16rne(float f) {
  union { float f; unsigned u; } v; v.f = f;
  return (v.u + 0x7FFFu + ((v.u >> 16) & 1u)) >> 16;
}
__device__ __forceinline__ unsigned pack2(float a, float b) {
  return b16rne(a) | (b16rne(b) << 16);
}
__device__ __forceinline__ float bflo(unsigned u) {
  union { unsigned q; float f; } x; x.q = u << 16; return x.f;
}
__device__ __forceinline__ float bfhi(unsigned u) {
  union { unsigned q; float f; } x; x.q = u & 0xFFFF0000u; return x.f;
}
__device__ __forceinline__ s16x8 as_s16x8(u32x4 u){ union{u32x4 a; s16x8 b;} x; x.a=u; return x.b; }
__device__ __forceinline__ s16x4 as_s16x4(u32x2 u){ union{u32x2 a; s16x4 b;} x; x.a=u; return x.b; }

// row-major [N][64]bf16 tile (128 B rows), XOR swizzle (G4)
__device__ __forceinline__ int swz128(int row, int bir) { return row*128 + (bir ^ ((row&7)<<4)); }
// V^T tile [64][512]bf16 (1024 B rows), 6-bit XOR swizzle
__device__ __forceinline__ int swzV(int c, int bir)    { return c*1024 + (bir ^ ((c&63)<<4)); }

__device__ __forceinline__ void loadrow(float (&x)[64], const float* __restrict__ p, int base, int t) {
#pragma unroll
  for (int c = 0; c < 64; ++c) x[c] = p[base + c*HW_ + t];
}

// LayerNorm over xv[64] then pack bf16 into buf row (swizzled); w/bb read via scalar cache
__device__ __forceinline__ void ln_pack_store(const float (&xv)[64], const float* __restrict__ w,
                                              const float* __restrict__ bb, char* buf, int row) {
  float s = 0.f;
#pragma unroll
  for (int c = 0; c < 64; ++c) s += xv[c];
  float mu = s * 0.015625f;
  float v = 0.f;
#pragma unroll
  for (int c = 0; c < 64; ++c) { float d = xv[c]-mu; v = fmaf(d,d,v); }
  float rs = rsqrtf(v*0.015625f + 1e-6f);
#pragma unroll
  for (int i = 0; i < 8; ++i) {
    u32x4 u;
#pragma unroll
    for (int e = 0; e < 4; ++e) {
      int c0 = i*8 + e*2;
      float y0 = (xv[c0  ]-mu)*rs*w[c0  ] + bb[c0  ];
      float y1 = (xv[c0+1]-mu)*rs*w[c0+1] + bb[c0+1];
      u[e] = pack2(y0, y1);
    }
    *(u32x4*)(buf + swz128(row, i*16)) = u;
  }
}

// stage 64x64 fp32 weight matrix (row-major [out][in]) -> bf16 LDS, swizzled
__device__ __forceinline__ void stageW(const float* __restrict__ Wg, char* bufW, int t) {
  int row = t >> 3, c0 = (t & 7) * 8;
  f32x4 f0 = *(const f32x4*)(Wg + row*64 + c0);
  f32x4 f1 = *(const f32x4*)(Wg + row*64 + c0 + 4);
  u32x4 u = { pack2(f0[0],f0[1]), pack2(f0[2],f0[3]), pack2(f1[0],f1[1]), pack2(f1[2],f1[3]) };
  *(u32x4*)(bufW + swz128(row, c0*2)) = u;
}

// stage x (NCHW row) -> V^T [c][w] bf16 LDS (native layout is already [c][w])
__device__ __forceinline__ void stageV(const float* __restrict__ x, int base, char* bufV, int t) {
  int c = t >> 3, w0 = (t & 7) * 64;
#pragma unroll
  for (int i = 0; i < 8; ++i) {
    int w = w0 + i*8;
    f32x4 f0 = *(const f32x4*)(x + base + c*HW_ + w);
    f32x4 f1 = *(const f32x4*)(x + base + c*HW_ + w + 4);
    u32x4 u = { pack2(f0[0],f0[1]), pack2(f0[2],f0[3]), pack2(f1[0],f1[1]), pack2(f1[2],f1[3]) };
    *(u32x4*)(bufV + swzV(c, w*2)) = u;
  }
}

// [512x64] @ W^T + bias via MFMA; in/out row-major bf16 swizzled LDS tiles
__device__ __forceinline__ void proj64(const char* bufIn, const char* bufW,
                                       const float* __restrict__ biasG,
                                       char* bufOut, int wave, int lane) {
  int g = lane >> 4, q15 = lane & 15;
  u32x4 a[4][2], wb[4][2];
#pragma unroll
  for (int mt = 0; mt < 4; ++mt)
#pragma unroll
    for (int h = 0; h < 2; ++h)
      a[mt][h] = *(const u32x4*)(bufIn + swz128(wave*64 + mt*16 + q15, h*64 + g*16));
#pragma unroll
  for (int ot = 0; ot < 4; ++ot)
#pragma unroll
    for (int h = 0; h < 2; ++h)
      wb[ot][h] = *(const u32x4*)(bufW + swz128(ot*16 + q15, h*64 + g*16));
#pragma unroll
  for (int mt = 0; mt < 4; ++mt) {
#pragma unroll
    for (int ot = 0; ot < 4; ++ot) {
      f32x4 z = {0.f,0.f,0.f,0.f};
      f32x4 acc = MFMA32(as_s16x8(a[mt][0]), as_s16x8(wb[ot][0]), z);
      acc = MFMA32(as_s16x8(a[mt][1]), as_s16x8(wb[ot][1]), acc);
      float bv = biasG[ot*16 + q15];
#pragma unroll
      for (int rr = 0; rr < 4; ++rr)
        *(short*)(bufOut + swz128(wave*64 + mt*16 + 4*g + rr, 2*(ot*16 + q15))) =
            (short)b16rne(acc[rr] + bv);
    }
  }
}

// pull own 64 q-rows as B-fragments (pre-scaled by QSCALE)
__device__ __forceinline__ void extract_q(const char* bufQ, int wave, int lane, s16x8 (&qf)[4][2]) {
  int g = lane >> 4, q15 = lane & 15;
#pragma unroll
  for (int qt = 0; qt < 4; ++qt)
#pragma unroll
    for (int h = 0; h < 2; ++h) {
      u32x4 u = *(const u32x4*)(bufQ + swz128(wave*64 + qt*16 + q15, h*64 + g*16));
#pragma unroll
      for (int e = 0; e < 4; ++e)
        u[e] = pack2(bflo(u[e])*QSCALE, bfhi(u[e])*QSCALE);
      qf[qt][h] = as_s16x8(u);
    }
}

// flash attention: K in bufK ([512][64] swz), V^T in bufV, Q-frags in regs
__device__ __forceinline__ void flash_pass(const char* bufK, const char* bufV, const s16x8 (&qf)[4][2],
                                           f32x4 (&O)[4][4], float (&lsum)[4], int lane) {
  int g = lane >> 4, q15 = lane & 15;
  float mref[4];
#pragma unroll
  for (int qt = 0; qt < 4; ++qt) {
    mref[qt] = -__builtin_inff(); lsum[qt] = 0.f;
#pragma unroll
    for (int ct = 0; ct < 4; ++ct) { f32x4 z = {0.f,0.f,0.f,0.f}; O[qt][ct] = z; }
  }
#pragma unroll 1
  for (int ch = 0; ch < 16; ++ch) {
    int kbase = ch * 32;
    u32x4 ka[2][2];
#pragma unroll
    for (int kb = 0; kb < 2; ++kb)
#pragma unroll
      for (int h = 0; h < 2; ++h)
        ka[kb][h] = *(const u32x4*)(bufK + swz128(kbase + kb*16 + q15, h*64 + g*16));
#pragma unroll
    for (int qt = 0; qt < 4; ++qt) {
      f32x4 z = {0.f,0.f,0.f,0.f};
      f32x4 a0 = MFMA32(as_s16x8(ka[0][0]), qf[qt][0], z);
      a0 = MFMA32(as_s16x8(ka[0][1]), qf[qt][1], a0);
      f32x4 a1 = MFMA32(as_s16x8(ka[1][0]), qf[qt][0], z);
      a1 = MFMA32(as_s16x8(ka[1][1]), qf[qt][1], a1);
      float cm = fmaxf(fmaxf(fmaxf(a0[0],a0[1]), fmaxf(a0[2],a0[3])),
                       fmaxf(fmaxf(a1[0],a1[1]), fmaxf(a1[2],a1[3])));
      cm = fmaxf(cm, __shfl_xor(cm, 16));
      cm = fmaxf(cm, __shfl_xor(cm, 32));
      if (__any(cm > mref[qt] + 8.f)) {       // deferred rescale (T13, log2 domain)
        float nm = fmaxf(mref[qt], cm);
        float corr = EXP2(mref[qt] - nm);
        lsum[qt] *= corr; mref[qt] = nm;
#pragma unroll
        for (int rr = 0; rr < 4; ++rr) {
          float cr = __shfl(corr, 4*g + rr);
#pragma unroll
          for (int ct = 0; ct < 4; ++ct) O[qt][ct][rr] *= cr;
        }
      }
      float p[8], sm = 0.f;
#pragma unroll
      for (int j = 0; j < 4; ++j) { p[j]   = EXP2(a0[j] - mref[qt]); sm += p[j]; }
#pragma unroll
      for (int j = 0; j < 4; ++j) { p[4+j] = EXP2(a1[j] - mref[qt]); sm += p[4+j]; }
      float s1 = sm + __shfl_xor(sm, 16);
      float s2 = s1 + __shfl_xor(s1, 32);
      lsum[qt] += s2;
      u32x2 pa0 = { pack2(p[0],p[1]), pack2(p[2],p[3]) };
      u32x2 pa1 = { pack2(p[4],p[5]), pack2(p[6],p[7]) };
      // V-fragments loaded at point of use (short live range; allocator freedom)
#pragma unroll
      for (int ct = 0; ct < 4; ++ct) {
        int c = ct*16 + q15;
        u32x2 v0 = *(const u32x2*)(bufV + swzV(c, (kbase + 4*g)*2));
        u32x2 v1 = *(const u32x2*)(bufV + swzV(c, (kbase + 16 + 4*g)*2));
        O[qt][ct] = MFMA16(as_s16x4(pa0), as_s16x4(v0), O[qt][ct]);
        O[qt][ct] = MFMA16(as_s16x4(pa1), as_s16x4(v1), O[qt][ct]);
      }
    }
  }
}

// normalize by 1/l and store O bf16 -> [512][64] swizzled tile
__device__ __forceinline__ void write_O(char* buf, const f32x4 (&O)[4][4], const float (&lsum)[4],
                                        int wave, int lane) {
  int g = lane >> 4, q15 = lane & 15;
#pragma unroll
  for (int qt = 0; qt < 4; ++qt) {
    float inv = 1.f / lsum[qt];
    float invr[4];
#pragma unroll
    for (int rr = 0; rr < 4; ++rr) invr[rr] = __shfl(inv, 4*g + rr);
#pragma unroll
    for (int ct = 0; ct < 4; ++ct)
#pragma unroll
      for (int rr = 0; rr < 4; ++rr)
        *(short*)(buf + swz128(wave*64 + qt*16 + 4*g + rr, 2*(ct*16 + q15))) =
            (short)b16rne(O[qt][ct][rr] * invr[rr]);
  }
}

// out = xres + coef*G, chunked (low register pressure); coef via scalar cache
__device__ __forceinline__ void epilogue_row(const char* bufG, const float* __restrict__ xres,
                                             const float* __restrict__ coef,
                                             float* __restrict__ outp, int base, int t) {
#pragma unroll
  for (int i = 0; i < 8; ++i) {
    u32x4 gvv = *(const u32x4*)(bufG + swz128(t, i*16));
#pragma unroll
    for (int e = 0; e < 4; ++e) {
      int o = i*8 + e*2;
      outp[base + o*HW_ + t]     = xres[base + o*HW_ + t]     + coef[o]   * bflo(gvv[e]);
      outp[base + (o+1)*HW_ + t] = xres[base + (o+1)*HW_ + t] + coef[o+1] * bfhi(gvv[e]);
    }
  }
}

__global__ __launch_bounds__(512)
__attribute__((amdgpu_waves_per_eu(2)))   // 2 waves/EU -> 256 unified VGPR+AGPR budget per wave
void scam_mfma(const float* __restrict__ xl, const float* __restrict__ xr,
               const float* __restrict__ nlw, const float* __restrict__ nlb,
               const float* __restrict__ nrw, const float* __restrict__ nrb,
               const float* __restrict__ l1w, const float* __restrict__ l1b,
               const float* __restrict__ r1w, const float* __restrict__ r1b,
               const float* __restrict__ l2w, const float* __restrict__ l2b,
               const float* __restrict__ r2w, const float* __restrict__ r2b,
               const float* __restrict__ beta, const float* __restrict__ gamma,
               float* __restrict__ out) {
  __shared__ __align__(16) char bufA[65536];
  __shared__ __align__(16) char bufB[65536];
  __shared__ __align__(16) char bufW[8192];

  const int t = threadIdx.x, lane = t & 63, wave = t >> 6;
  const int r = blockIdx.x, b = r >> 7, h = r & 127;
  const int base = b*CHW_ + h*512;

  // P0: LN(x_l) -> A ; W1l -> W
  { float xv[64]; loadrow(xv, xl, base, t); ln_pack_store(xv, nlw, nlb, bufA, t); }
  stageW(l1w, bufW, t);
  __syncthreads();
  // P1: Q_l = LN(x_l)@W1l^T + b1l -> B
  proj64(bufA, bufW, l1b, bufB, wave, lane);
  __syncthreads();
  // P2: qfL <- B ; LN(x_r) -> A ; W1r -> W
  s16x8 qfL[4][2];
  extract_q(bufB, wave, lane, qfL);
  { float xv[64]; loadrow(xv, xr, base, t); ln_pack_store(xv, nrw, nrb, bufA, t); }
  stageW(r1w, bufW, t);
  __syncthreads();
  // P3: Q_r -> B  (qfL lives in regs)
  proj64(bufA, bufW, r1b, bufB, wave, lane);
  __syncthreads();
  // P4: V^T = x_r -> A ; W2r -> W
  stageV(xr, base, bufA, t);
  stageW(r2w, bufW, t);
  __syncthreads();
  // A1: F_r2l = Attn(Q_l, Q_r, x_r)
  f32x4 O[4][4]; float lsum[4];
  flash_pass(bufB, bufA, qfL, O, lsum, lane);
  // Q_r tile (B) still resident -- extract qfR only now (keeps A1 pressure low)
  s16x8 qfR[4][2];
  extract_q(bufB, wave, lane, qfR);
  __syncthreads();
  // P5: O1 -> A (V dead)
  write_O(bufA, O, lsum, wave, lane);
  __syncthreads();
  // E1a: G1 = O1@W2r^T + b2r -> B
  proj64(bufA, bufW, r2b, bufB, wave, lane);
  __syncthreads();
  // E1b: out_l = x_l + beta*G1 ; then LN(x_l) -> A ; W1l -> W
  epilogue_row(bufB, xl, beta, out, base, t);
  { float xv[64]; loadrow(xv, xl, base, t); ln_pack_store(xv, nlw, nlb, bufA, t); }
  stageW(l1w, bufW, t);
  __syncthreads();
  // P7: Q_l -> B
  proj64(bufA, bufW, l1b, bufB, wave, lane);
  __syncthreads();
  // P8: V^T = x_l -> A ; W2l -> W
  stageV(xl, base, bufA, t);
  stageW(l2w, bufW, t);
  __syncthreads();
  // A2: F_l2r = Attn(Q_r, Q_l, x_l)
  flash_pass(bufB, bufA, qfR, O, lsum, lane);
  __syncthreads();
  // P9: O2 -> A
  write_O(bufA, O, lsum, wave, lane);
  __syncthreads();
  // E2a: G2 = O2@W2l^T + b2l -> B
  proj64(bufA, bufW, l2b, bufB, wave, lane);
  __syncthreads();
  // E2b: out_r = x_r + gamma*G2
  epilogue_row(bufB, xr, gamma, out + OUTR_, base, t);
}

extern "C" void kernel_launch(void* const* d_in, const int* in_sizes, int n_in,
                              void* d_out, int out_size, void* d_ws, size_t ws_size,
                              hipStream_t stream) {
  (void)in_sizes; (void)n_in; (void)d_ws; (void)ws_size; (void)out_size;
  scam_mfma<<<dim3(512), dim3(512), 0, stream>>>(
      (const float*)d_in[0],  (const float*)d_in[1],
      (const float*)d_in[2],  (const float*)d_in[3],
      (const float*)d_in[4],  (const float*)d_in[5],
      (const float*)d_in[6],  (const float*)d_in[7],
      (const float*)d_in[8],  (const float*)d_in[9],
      (const float*)d_in[10], (const float*)d_in[11],
      (const float*)d_in[12], (const float*)d_in[13],
      (const float*)d_in[14], (const float*)d_in[15],
      (float*)d_out);
}

// Round 6
// 428.705 us; speedup vs baseline: 39.6722x; 1.4334x over previous
//
#include <hip/hip_runtime.h>

#define HW_   65536        // H*W
#define CHW_  4194304      // C*H*W
#define OUTR_ 16777216     // offset of out_r in d_out (floats)

typedef __attribute__((ext_vector_type(4))) float    f32x4;
typedef __attribute__((ext_vector_type(8))) short    s16x8;
typedef __attribute__((ext_vector_type(4))) short    s16x4;
typedef __attribute__((ext_vector_type(4))) unsigned u32x4;
typedef __attribute__((ext_vector_type(2))) unsigned u32x2;

#define MFMA32(A,B,C) __builtin_amdgcn_mfma_f32_16x16x32_bf16((A),(B),(C),0,0,0)

#if __has_builtin(__builtin_amdgcn_mfma_f32_16x16x16bf16_1k)
#define MFMA16(A,B,C) __builtin_amdgcn_mfma_f32_16x16x16bf16_1k((A),(B),(C),0,0,0)
#else
__device__ __forceinline__ f32x4 mfma16_asm(s16x4 a, s16x4 b, f32x4 c){
  asm volatile("v_mfma_f32_16x16x16_bf16 %0, %1, %2, %0\n\ts_nop 7" : "+v"(c) : "v"(a), "v"(b));
  return c;
}
#define MFMA16(A,B,C) mfma16_asm((A),(B),(C))
#endif

#define EXP2(x) exp2f(x)
#define QSCALE 0.18033688011112043f   // C^-0.5 * log2(e), folded into Q at extraction

__device__ __forceinline__ unsigned b16rne(float f) {
  union { float f; unsigned u; } v; v.f = f;
  return (v.u + 0x7FFFu + ((v.u >> 16) & 1u)) >> 16;
}
__device__ __forceinline__ unsigned pack2(float a, float b) {
  return b16rne(a) | (b16rne(b) << 16);
}
__device__ __forceinline__ float bflo(unsigned u) {
  union { unsigned q; float f; } x; x.q = u << 16; return x.f;
}
__device__ __forceinline__ float bfhi(unsigned u) {
  union { unsigned q; float f; } x; x.q = u & 0xFFFF0000u; return x.f;
}
__device__ __forceinline__ s16x8 as_s16x8(u32x4 u){ union{u32x4 a; s16x8 b;} x; x.a=u; return x.b; }
__device__ __forceinline__ s16x4 as_s16x4(u32x2 u){ union{u32x2 a; s16x4 b;} x; x.a=u; return x.b; }

// row-major [N][64]bf16 tile (128 B rows), XOR swizzle (G4)
__device__ __forceinline__ int swz128(int row, int bir) { return row*128 + (bir ^ ((row&7)<<4)); }
// V^T tile [64][512]bf16 (1024 B rows), 6-bit XOR swizzle
__device__ __forceinline__ int swzV(int c, int bir)    { return c*1024 + (bir ^ ((c&63)<<4)); }

// ---- pair-split LayerNorm: thread handles 32 channels of pixel `pix` ----
__device__ __forceinline__ void ln32(const float* __restrict__ p, int base, int pix, int half,
                                     const float* __restrict__ w, const float* __restrict__ bb,
                                     char* buf, float* redS, float* redSS) {
  const int c0 = half*32;
  float xv[32], s = 0.f, ss = 0.f;
#pragma unroll
  for (int i = 0; i < 32; ++i) {
    float v = p[base + (c0+i)*HW_ + pix];
    xv[i] = v; s += v; ss = fmaf(v, v, ss);
  }
  redS[half*512 + pix] = s; redSS[half*512 + pix] = ss;
  __syncthreads();
  float st  = redS[pix]  + redS[512 + pix];
  float sst = redSS[pix] + redSS[512 + pix];
  float mu = st * 0.015625f;
  float rs = rsqrtf(fmaxf(sst * 0.015625f - mu*mu, 0.f) + 1e-6f);
#pragma unroll
  for (int i2 = 0; i2 < 4; ++i2) {
    u32x4 u;
#pragma unroll
    for (int e = 0; e < 4; ++e) {
      int i = i2*8 + e*2;
      float y0 = (xv[i  ]-mu)*rs*w[c0+i  ] + bb[c0+i  ];
      float y1 = (xv[i+1]-mu)*rs*w[c0+i+1] + bb[c0+i+1];
      u[e] = pack2(y0, y1);
    }
    *(u32x4*)(buf + swz128(pix, half*64 + i2*16)) = u;
  }
}

// stage 64x64 fp32 weight matrix -> bf16 LDS, swizzled (first 512 threads)
__device__ __forceinline__ void stageW(const float* __restrict__ Wg, char* bufW, int t) {
  int row = t >> 3, c0 = (t & 7) * 8;
  f32x4 f0 = *(const f32x4*)(Wg + row*64 + c0);
  f32x4 f1 = *(const f32x4*)(Wg + row*64 + c0 + 4);
  u32x4 u = { pack2(f0[0],f0[1]), pack2(f0[2],f0[3]), pack2(f1[0],f1[1]), pack2(f1[2],f1[3]) };
  *(u32x4*)(bufW + swz128(row, c0*2)) = u;
}

// stage x (NCHW row) -> V^T [c][w] bf16 LDS; 1024 threads, 32 px each
__device__ __forceinline__ void stageV(const float* __restrict__ x, int base, char* bufV, int t) {
  int c = t >> 4, w0 = (t & 15) * 32;
#pragma unroll
  for (int i = 0; i < 4; ++i) {
    int w = w0 + i*8;
    f32x4 f0 = *(const f32x4*)(x + base + c*HW_ + w);
    f32x4 f1 = *(const f32x4*)(x + base + c*HW_ + w + 4);
    u32x4 u = { pack2(f0[0],f0[1]), pack2(f0[2],f0[3]), pack2(f1[0],f1[1]), pack2(f1[2],f1[3]) };
    *(u32x4*)(bufV + swzV(c, w*2)) = u;
  }
}

// [512x64] @ W^T + bias via MFMA; 16 waves x 2 row-tiles
__device__ __forceinline__ void proj64(const char* bufIn, const char* bufW,
                                       const float* __restrict__ biasG,
                                       char* bufOut, int wave, int lane) {
  int g = lane >> 4, q15 = lane & 15;
  u32x4 a[2][2], wb[4][2];
#pragma unroll
  for (int mt = 0; mt < 2; ++mt)
#pragma unroll
    for (int h = 0; h < 2; ++h)
      a[mt][h] = *(const u32x4*)(bufIn + swz128(wave*32 + mt*16 + q15, h*64 + g*16));
#pragma unroll
  for (int ot = 0; ot < 4; ++ot)
#pragma unroll
    for (int h = 0; h < 2; ++h)
      wb[ot][h] = *(const u32x4*)(bufW + swz128(ot*16 + q15, h*64 + g*16));
#pragma unroll
  for (int mt = 0; mt < 2; ++mt) {
#pragma unroll
    for (int ot = 0; ot < 4; ++ot) {
      f32x4 z = {0.f,0.f,0.f,0.f};
      f32x4 acc = MFMA32(as_s16x8(a[mt][0]), as_s16x8(wb[ot][0]), z);
      acc = MFMA32(as_s16x8(a[mt][1]), as_s16x8(wb[ot][1]), acc);
      float bv = biasG[ot*16 + q15];
#pragma unroll
      for (int rr = 0; rr < 4; ++rr)
        *(short*)(bufOut + swz128(wave*32 + mt*16 + 4*g + rr, 2*(ot*16 + q15))) =
            (short)b16rne(acc[rr] + bv);
    }
  }
}

// pull own 32 q-rows as B-fragments (pre-scaled by QSCALE)
__device__ __forceinline__ void extract_q(const char* bufQ, int wave, int lane, s16x8 (&qf)[2][2]) {
  int g = lane >> 4, q15 = lane & 15;
#pragma unroll
  for (int qt = 0; qt < 2; ++qt)
#pragma unroll
    for (int h = 0; h < 2; ++h) {
      u32x4 u = *(const u32x4*)(bufQ + swz128(wave*32 + qt*16 + q15, h*64 + g*16));
#pragma unroll
      for (int e = 0; e < 4; ++e)
        u[e] = pack2(bflo(u[e])*QSCALE, bfhi(u[e])*QSCALE);
      qf[qt][h] = as_s16x8(u);
    }
}

// flash attention: K in bufK ([512][64] swz), V^T in bufV, Q-frags in regs
__device__ __forceinline__ void flash_pass(const char* bufK, const char* bufV, const s16x8 (&qf)[2][2],
                                           f32x4 (&O)[2][4], float (&lsum)[2], int lane) {
  int g = lane >> 4, q15 = lane & 15;
  float mref[2];
#pragma unroll
  for (int qt = 0; qt < 2; ++qt) {
    mref[qt] = -__builtin_inff(); lsum[qt] = 0.f;
#pragma unroll
    for (int ct = 0; ct < 4; ++ct) { f32x4 z = {0.f,0.f,0.f,0.f}; O[qt][ct] = z; }
  }
#pragma unroll 1
  for (int ch = 0; ch < 16; ++ch) {
    int kbase = ch * 32;
    u32x4 ka[2][2];
#pragma unroll
    for (int kb = 0; kb < 2; ++kb)
#pragma unroll
      for (int h = 0; h < 2; ++h)
        ka[kb][h] = *(const u32x4*)(bufK + swz128(kbase + kb*16 + q15, h*64 + g*16));
#pragma unroll
    for (int qt = 0; qt < 2; ++qt) {
      f32x4 z = {0.f,0.f,0.f,0.f};
      f32x4 a0 = MFMA32(as_s16x8(ka[0][0]), qf[qt][0], z);
      a0 = MFMA32(as_s16x8(ka[0][1]), qf[qt][1], a0);
      f32x4 a1 = MFMA32(as_s16x8(ka[1][0]), qf[qt][0], z);
      a1 = MFMA32(as_s16x8(ka[1][1]), qf[qt][1], a1);
      float cm = fmaxf(fmaxf(fmaxf(a0[0],a0[1]), fmaxf(a0[2],a0[3])),
                       fmaxf(fmaxf(a1[0],a1[1]), fmaxf(a1[2],a1[3])));
      cm = fmaxf(cm, __shfl_xor(cm, 16));
      cm = fmaxf(cm, __shfl_xor(cm, 32));
      if (__any(cm > mref[qt] + 8.f)) {       // deferred rescale (T13, log2 domain)
        float nm = fmaxf(mref[qt], cm);
        float corr = EXP2(mref[qt] - nm);
        lsum[qt] *= corr; mref[qt] = nm;
#pragma unroll
        for (int rr = 0; rr < 4; ++rr) {
          float cr = __shfl(corr, 4*g + rr);
#pragma unroll
          for (int ct = 0; ct < 4; ++ct) O[qt][ct][rr] *= cr;
        }
      }
      float p[8], sm = 0.f;
#pragma unroll
      for (int j = 0; j < 4; ++j) { p[j]   = EXP2(a0[j] - mref[qt]); sm += p[j]; }
#pragma unroll
      for (int j = 0; j < 4; ++j) { p[4+j] = EXP2(a1[j] - mref[qt]); sm += p[4+j]; }
      float s1 = sm + __shfl_xor(sm, 16);
      float s2 = s1 + __shfl_xor(s1, 32);
      lsum[qt] += s2;
      u32x2 pa0 = { pack2(p[0],p[1]), pack2(p[2],p[3]) };
      u32x2 pa1 = { pack2(p[4],p[5]), pack2(p[6],p[7]) };
#pragma unroll
      for (int ct = 0; ct < 4; ++ct) {
        int c = ct*16 + q15;
        u32x2 v0 = *(const u32x2*)(bufV + swzV(c, (kbase + 4*g)*2));
        u32x2 v1 = *(const u32x2*)(bufV + swzV(c, (kbase + 16 + 4*g)*2));
        O[qt][ct] = MFMA16(as_s16x4(pa0), as_s16x4(v0), O[qt][ct]);
        O[qt][ct] = MFMA16(as_s16x4(pa1), as_s16x4(v1), O[qt][ct]);
      }
    }
  }
}

// normalize by 1/l and store O bf16 -> [512][64] swizzled tile
__device__ __forceinline__ void write_O(char* buf, const f32x4 (&O)[2][4], const float (&lsum)[2],
                                        int wave, int lane) {
  int g = lane >> 4, q15 = lane & 15;
#pragma unroll
  for (int qt = 0; qt < 2; ++qt) {
    float inv = 1.f / lsum[qt];
    float invr[4];
#pragma unroll
    for (int rr = 0; rr < 4; ++rr) invr[rr] = __shfl(inv, 4*g + rr);
#pragma unroll
    for (int ct = 0; ct < 4; ++ct)
#pragma unroll
      for (int rr = 0; rr < 4; ++rr)
        *(short*)(buf + swz128(wave*32 + qt*16 + 4*g + rr, 2*(ct*16 + q15))) =
            (short)b16rne(O[qt][ct][rr] * invr[rr]);
  }
}

// plain epilogue: out = xres + coef*G (pair-split, 32 ch per thread)
__device__ __forceinline__ void epi32(const char* bufG, const float* __restrict__ xres,
                                      const float* __restrict__ coef, float* __restrict__ outp,
                                      int base, int pix, int half) {
  const int c0 = half*32;
#pragma unroll
  for (int i2 = 0; i2 < 4; ++i2) {
    u32x4 gv = *(const u32x4*)(bufG + swz128(pix, half*64 + i2*16));
#pragma unroll
    for (int e = 0; e < 4; ++e) {
      int i = i2*8 + e*2;
      int idx = base + (c0+i)*HW_ + pix;
      outp[idx]       = xres[idx]       + coef[c0+i]   * bflo(gv[e]);
      outp[idx + HW_] = xres[idx + HW_] + coef[c0+i+1] * bfhi(gv[e]);
    }
  }
}

// fused epilogue + LayerNorm of the residual input (reads xres once)
__device__ __forceinline__ void epi_ln(const char* bufG, const float* __restrict__ xres,
                                       const float* __restrict__ coef, float* __restrict__ outp,
                                       const float* __restrict__ w, const float* __restrict__ bb,
                                       char* bufLN, int base, int pix, int half,
                                       float* redS, float* redSS) {
  const int c0 = half*32;
  float xv[32], s = 0.f, ss = 0.f;
#pragma unroll
  for (int i2 = 0; i2 < 4; ++i2) {
    u32x4 gv = *(const u32x4*)(bufG + swz128(pix, half*64 + i2*16));
#pragma unroll
    for (int e = 0; e < 4; ++e) {
      int i = i2*8 + e*2;
      int idx = base + (c0+i)*HW_ + pix;
      float x0 = xres[idx], x1 = xres[idx + HW_];
      xv[i] = x0; xv[i+1] = x1;
      s += x0 + x1; ss = fmaf(x0,x0,ss); ss = fmaf(x1,x1,ss);
      outp[idx]       = x0 + coef[c0+i]   * bflo(gv[e]);
      outp[idx + HW_] = x1 + coef[c0+i+1] * bfhi(gv[e]);
    }
  }
  redS[half*512 + pix] = s; redSS[half*512 + pix] = ss;
  __syncthreads();
  float st  = redS[pix]  + redS[512 + pix];
  float sst = redSS[pix] + redSS[512 + pix];
  float mu = st * 0.015625f;
  float rs = rsqrtf(fmaxf(sst * 0.015625f - mu*mu, 0.f) + 1e-6f);
#pragma unroll
  for (int i2 = 0; i2 < 4; ++i2) {
    u32x4 u;
#pragma unroll
    for (int e = 0; e < 4; ++e) {
      int i = i2*8 + e*2;
      float y0 = (xv[i  ]-mu)*rs*w[c0+i  ] + bb[c0+i  ];
      float y1 = (xv[i+1]-mu)*rs*w[c0+i+1] + bb[c0+i+1];
      u[e] = pack2(y0, y1);
    }
    *(u32x4*)(bufLN + swz128(pix, half*64 + i2*16)) = u;
  }
}

__global__ __launch_bounds__(1024)
void scam_mfma(const float* __restrict__ xl, const float* __restrict__ xr,
               const float* __restrict__ nlw, const float* __restrict__ nlb,
               const float* __restrict__ nrw, const float* __restrict__ nrb,
               const float* __restrict__ l1w, const float* __restrict__ l1b,
               const float* __restrict__ r1w, const float* __restrict__ r1b,
               const float* __restrict__ l2w, const float* __restrict__ l2b,
               const float* __restrict__ r2w, const float* __restrict__ r2b,
               const float* __restrict__ beta, const float* __restrict__ gamma,
               float* __restrict__ out) {
  __shared__ __align__(16) char bufA[65536];
  __shared__ __align__(16) char bufB[65536];
  __shared__ __align__(16) char bufW[8192];
  __shared__ float redS[1024];
  __shared__ float redSS[1024];

  const int t = threadIdx.x, lane = t & 63, wave = t >> 6;
  const int pix = t & 511, half = t >> 9;
  const int r = blockIdx.x, b = r >> 7, h = r & 127;
  const int base = b*CHW_ + h*512;

  // P0: W1l -> W ; LN(x_l) -> A
  if (t < 512) stageW(l1w, bufW, t);
  ln32(xl, base, pix, half, nlw, nlb, bufA, redS, redSS);
  __syncthreads();
  // P1: Q_l = LN(x_l)@W1l^T + b1l -> B
  proj64(bufA, bufW, l1b, bufB, wave, lane);
  __syncthreads();
  // P2: qfL <- B ; W1r -> W ; LN(x_r) -> A
  s16x8 qfL[2][2];
  extract_q(bufB, wave, lane, qfL);
  if (t < 512) stageW(r1w, bufW, t);
  ln32(xr, base, pix, half, nrw, nrb, bufA, redS, redSS);
  __syncthreads();
  // P3: Q_r -> B
  proj64(bufA, bufW, r1b, bufB, wave, lane);
  __syncthreads();
  // P4: V^T = x_r -> A ; W2r -> W
  stageV(xr, base, bufA, t);
  if (t < 512) stageW(r2w, bufW, t);
  __syncthreads();
  // A1: F_r2l = Attn(Q_l, Q_r, x_r); then harvest qfR (Q_r tile still in B)
  f32x4 O[2][4]; float lsum[2];
  flash_pass(bufB, bufA, qfL, O, lsum, lane);
  s16x8 qfR[2][2];
  extract_q(bufB, wave, lane, qfR);
  __syncthreads();
  // P5: O1 -> A
  write_O(bufA, O, lsum, wave, lane);
  __syncthreads();
  // E1a: G1 = O1@W2r^T + b2r -> B
  proj64(bufA, bufW, r2b, bufB, wave, lane);
  __syncthreads();
  // E1b: out_l = x_l + beta*G1 (fused with LN(x_l) -> A) ; W1l -> W
  if (t < 512) stageW(l1w, bufW, t);
  epi_ln(bufB, xl, beta, out, nlw, nlb, bufA, base, pix, half, redS, redSS);
  __syncthreads();
  // P7: Q_l -> B
  proj64(bufA, bufW, l1b, bufB, wave, lane);
  __syncthreads();
  // P8: V^T = x_l -> A ; W2l -> W
  stageV(xl, base, bufA, t);
  if (t < 512) stageW(l2w, bufW, t);
  __syncthreads();
  // A2: F_l2r = Attn(Q_r, Q_l, x_l)
  flash_pass(bufB, bufA, qfR, O, lsum, lane);
  __syncthreads();
  // P9: O2 -> A
  write_O(bufA, O, lsum, wave, lane);
  __syncthreads();
  // E2a: G2 = O2@W2l^T + b2l -> B
  proj64(bufA, bufW, l2b, bufB, wave, lane);
  __syncthreads();
  // E2b: out_r = x_r + gamma*G2
  epi32(bufB, xr, gamma, out + OUTR_, base, pix, half);
}

extern "C" void kernel_launch(void* const* d_in, const int* in_sizes, int n_in,
                              void* d_out, int out_size, void* d_ws, size_t ws_size,
                              hipStream_t stream) {
  (void)in_sizes; (void)n_in; (void)d_ws; (void)ws_size; (void)out_size;
  scam_mfma<<<dim3(512), dim3(1024), 0, stream>>>(
      (const float*)d_in[0],  (const float*)d_in[1],
      (const float*)d_in[2],  (const float*)d_in[3],
      (const float*)d_in[4],  (const float*)d_in[5],
      (const float*)d_in[6],  (const float*)d_in[7],
      (const float*)d_in[8],  (const float*)d_in[9],
      (const float*)d_in[10], (const float*)d_in[11],
      (const float*)d_in[12], (const float*)d_in[13],
      (const float*)d_in[14], (const float*)d_in[15],
      (float*)d_out);
}

// Round 7
// 423.274 us; speedup vs baseline: 40.1812x; 1.0128x over previous
//
#include <hip/hip_runtime.h>

#define HW_   65536        // H*W
#define CHW_  4194304      // C*H*W
#define OUTR_ 16777216     // offset of out_r in d_out (floats)

typedef __attribute__((ext_vector_type(4))) float    f32x4;
typedef __attribute__((ext_vector_type(8))) short    s16x8;
typedef __attribute__((ext_vector_type(4))) short    s16x4;
typedef __attribute__((ext_vector_type(4))) unsigned u32x4;
typedef __attribute__((ext_vector_type(2))) unsigned u32x2;

#define MFMA32(A,B,C) __builtin_amdgcn_mfma_f32_16x16x32_bf16((A),(B),(C),0,0,0)

#if __has_builtin(__builtin_amdgcn_mfma_f32_16x16x16bf16_1k)
#define MFMA16(A,B,C) __builtin_amdgcn_mfma_f32_16x16x16bf16_1k((A),(B),(C),0,0,0)
#else
__device__ __forceinline__ f32x4 mfma16_asm(s16x4 a, s16x4 b, f32x4 c){
  asm volatile("v_mfma_f32_16x16x16_bf16 %0, %1, %2, %0\n\ts_nop 7" : "+v"(c) : "v"(a), "v"(b));
  return c;
}
#define MFMA16(A,B,C) mfma16_asm((A),(B),(C))
#endif

#define EXP2(x) exp2f(x)
#define QSCALE 0.18033688011112043f   // C^-0.5 * log2(e), folded into Q at extraction

__device__ __forceinline__ unsigned b16rne(float f) {
  union { float f; unsigned u; } v; v.f = f;
  return (v.u + 0x7FFFu + ((v.u >> 16) & 1u)) >> 16;
}
__device__ __forceinline__ unsigned pack2(float a, float b) {
  return b16rne(a) | (b16rne(b) << 16);
}
__device__ __forceinline__ float bflo(unsigned u) {
  union { unsigned q; float f; } x; x.q = u << 16; return x.f;
}
__device__ __forceinline__ float bfhi(unsigned u) {
  union { unsigned q; float f; } x; x.q = u & 0xFFFF0000u; return x.f;
}
__device__ __forceinline__ s16x8 as_s16x8(u32x4 u){ union{u32x4 a; s16x8 b;} x; x.a=u; return x.b; }
__device__ __forceinline__ s16x4 as_s16x4(u32x2 u){ union{u32x2 a; s16x4 b;} x; x.a=u; return x.b; }

// row-major [N][64]bf16 tile (128 B rows), XOR swizzle (G4)
__device__ __forceinline__ int swz128(int row, int bir) { return row*128 + (bir ^ ((row&7)<<4)); }
// V^T tile [64][512]bf16 (1024 B rows), 6-bit XOR swizzle
__device__ __forceinline__ int swzV(int c, int bir)    { return c*1024 + (bir ^ ((c&63)<<4)); }

// ---- pair-split LayerNorm: thread handles 32 channels of pixel `pix` ----
__device__ __forceinline__ void ln32(const float* __restrict__ p, int base, int pix, int half,
                                     const float* __restrict__ w, const float* __restrict__ bb,
                                     char* buf, float* redS, float* redSS) {
  const int c0 = half*32;
  float xv[32], s = 0.f, ss = 0.f;
#pragma unroll
  for (int i = 0; i < 32; ++i) {
    float v = p[base + (c0+i)*HW_ + pix];
    xv[i] = v; s += v; ss = fmaf(v, v, ss);
  }
  redS[half*512 + pix] = s; redSS[half*512 + pix] = ss;
  __syncthreads();
  float st  = redS[pix]  + redS[512 + pix];
  float sst = redSS[pix] + redSS[512 + pix];
  float mu = st * 0.015625f;
  float rs = rsqrtf(fmaxf(sst * 0.015625f - mu*mu, 0.f) + 1e-6f);
#pragma unroll
  for (int i2 = 0; i2 < 4; ++i2) {
    u32x4 u;
#pragma unroll
    for (int e = 0; e < 4; ++e) {
      int i = i2*8 + e*2;
      float y0 = (xv[i  ]-mu)*rs*w[c0+i  ] + bb[c0+i  ];
      float y1 = (xv[i+1]-mu)*rs*w[c0+i+1] + bb[c0+i+1];
      u[e] = pack2(y0, y1);
    }
    *(u32x4*)(buf + swz128(pix, half*64 + i2*16)) = u;
  }
}

// stage 64x64 fp32 weight matrix -> bf16 LDS, swizzled (first 512 threads)
__device__ __forceinline__ void stageW(const float* __restrict__ Wg, char* bufW, int t) {
  int row = t >> 3, c0 = (t & 7) * 8;
  f32x4 f0 = *(const f32x4*)(Wg + row*64 + c0);
  f32x4 f1 = *(const f32x4*)(Wg + row*64 + c0 + 4);
  u32x4 u = { pack2(f0[0],f0[1]), pack2(f0[2],f0[3]), pack2(f1[0],f1[1]), pack2(f1[2],f1[3]) };
  *(u32x4*)(bufW + swz128(row, c0*2)) = u;
}

// stage x (NCHW row) -> V^T [c][w] bf16 LDS; 1024 threads, 32 px each
__device__ __forceinline__ void stageV(const float* __restrict__ x, int base, char* bufV, int t) {
  int c = t >> 4, w0 = (t & 15) * 32;
#pragma unroll
  for (int i = 0; i < 4; ++i) {
    int w = w0 + i*8;
    f32x4 f0 = *(const f32x4*)(x + base + c*HW_ + w);
    f32x4 f1 = *(const f32x4*)(x + base + c*HW_ + w + 4);
    u32x4 u = { pack2(f0[0],f0[1]), pack2(f0[2],f0[3]), pack2(f1[0],f1[1]), pack2(f1[2],f1[3]) };
    *(u32x4*)(bufV + swzV(c, w*2)) = u;
  }
}

// [512x64] @ W^T + bias via MFMA; 16 waves x 2 row-tiles
__device__ __forceinline__ void proj64(const char* bufIn, const char* bufW,
                                       const float* __restrict__ biasG,
                                       char* bufOut, int wave, int lane) {
  int g = lane >> 4, q15 = lane & 15;
  u32x4 a[2][2], wb[4][2];
#pragma unroll
  for (int mt = 0; mt < 2; ++mt)
#pragma unroll
    for (int h = 0; h < 2; ++h)
      a[mt][h] = *(const u32x4*)(bufIn + swz128(wave*32 + mt*16 + q15, h*64 + g*16));
#pragma unroll
  for (int ot = 0; ot < 4; ++ot)
#pragma unroll
    for (int h = 0; h < 2; ++h)
      wb[ot][h] = *(const u32x4*)(bufW + swz128(ot*16 + q15, h*64 + g*16));
#pragma unroll
  for (int mt = 0; mt < 2; ++mt) {
#pragma unroll
    for (int ot = 0; ot < 4; ++ot) {
      f32x4 z = {0.f,0.f,0.f,0.f};
      f32x4 acc = MFMA32(as_s16x8(a[mt][0]), as_s16x8(wb[ot][0]), z);
      acc = MFMA32(as_s16x8(a[mt][1]), as_s16x8(wb[ot][1]), acc);
      float bv = biasG[ot*16 + q15];
#pragma unroll
      for (int rr = 0; rr < 4; ++rr)
        *(short*)(bufOut + swz128(wave*32 + mt*16 + 4*g + rr, 2*(ot*16 + q15))) =
            (short)b16rne(acc[rr] + bv);
    }
  }
}

// pull own 32 q-rows as B-fragments (pre-scaled by QSCALE)
__device__ __forceinline__ void extract_q(const char* bufQ, int wave, int lane, s16x8 (&qf)[2][2]) {
  int g = lane >> 4, q15 = lane & 15;
#pragma unroll
  for (int qt = 0; qt < 2; ++qt)
#pragma unroll
    for (int h = 0; h < 2; ++h) {
      u32x4 u = *(const u32x4*)(bufQ + swz128(wave*32 + qt*16 + q15, h*64 + g*16));
#pragma unroll
      for (int e = 0; e < 4; ++e)
        u[e] = pack2(bflo(u[e])*QSCALE, bfhi(u[e])*QSCALE);
      qf[qt][h] = as_s16x8(u);
    }
}

// flash attention: K in bufK ([512][64] swz), V^T in bufV, Q-frags in regs
__device__ __forceinline__ void flash_pass(const char* bufK, const char* bufV, const s16x8 (&qf)[2][2],
                                           f32x4 (&O)[2][4], float (&lsum)[2], int lane) {
  int g = lane >> 4, q15 = lane & 15;
  float mref[2];
#pragma unroll
  for (int qt = 0; qt < 2; ++qt) {
    mref[qt] = -__builtin_inff(); lsum[qt] = 0.f;
#pragma unroll
    for (int ct = 0; ct < 4; ++ct) { f32x4 z = {0.f,0.f,0.f,0.f}; O[qt][ct] = z; }
  }
#pragma unroll 1
  for (int ch = 0; ch < 16; ++ch) {
    int kbase = ch * 32;
    u32x4 ka[2][2];
#pragma unroll
    for (int kb = 0; kb < 2; ++kb)
#pragma unroll
      for (int h = 0; h < 2; ++h)
        ka[kb][h] = *(const u32x4*)(bufK + swz128(kbase + kb*16 + q15, h*64 + g*16));
#pragma unroll
    for (int qt = 0; qt < 2; ++qt) {
      f32x4 z = {0.f,0.f,0.f,0.f};
      f32x4 a0 = MFMA32(as_s16x8(ka[0][0]), qf[qt][0], z);
      a0 = MFMA32(as_s16x8(ka[0][1]), qf[qt][1], a0);
      f32x4 a1 = MFMA32(as_s16x8(ka[1][0]), qf[qt][0], z);
      a1 = MFMA32(as_s16x8(ka[1][1]), qf[qt][1], a1);
      float cm = fmaxf(fmaxf(fmaxf(a0[0],a0[1]), fmaxf(a0[2],a0[3])),
                       fmaxf(fmaxf(a1[0],a1[1]), fmaxf(a1[2],a1[3])));
      cm = fmaxf(cm, __shfl_xor(cm, 16));
      cm = fmaxf(cm, __shfl_xor(cm, 32));
      if (__any(cm > mref[qt] + 8.f)) {       // deferred rescale (T13, log2 domain)
        float nm = fmaxf(mref[qt], cm);
        float corr = EXP2(mref[qt] - nm);
        lsum[qt] *= corr; mref[qt] = nm;
#pragma unroll
        for (int rr = 0; rr < 4; ++rr) {
          float cr = __shfl(corr, 4*g + rr);
#pragma unroll
          for (int ct = 0; ct < 4; ++ct) O[qt][ct][rr] *= cr;
        }
      }
      float p[8], sm = 0.f;
#pragma unroll
      for (int j = 0; j < 4; ++j) { p[j]   = EXP2(a0[j] - mref[qt]); sm += p[j]; }
#pragma unroll
      for (int j = 0; j < 4; ++j) { p[4+j] = EXP2(a1[j] - mref[qt]); sm += p[4+j]; }
      float s1 = sm + __shfl_xor(sm, 16);
      float s2 = s1 + __shfl_xor(s1, 32);
      lsum[qt] += s2;
      u32x2 pa0 = { pack2(p[0],p[1]), pack2(p[2],p[3]) };
      u32x2 pa1 = { pack2(p[4],p[5]), pack2(p[6],p[7]) };
#pragma unroll
      for (int ct = 0; ct < 4; ++ct) {
        int c = ct*16 + q15;
        u32x2 v0 = *(const u32x2*)(bufV + swzV(c, (kbase + 4*g)*2));
        u32x2 v1 = *(const u32x2*)(bufV + swzV(c, (kbase + 16 + 4*g)*2));
        O[qt][ct] = MFMA16(as_s16x4(pa0), as_s16x4(v0), O[qt][ct]);
        O[qt][ct] = MFMA16(as_s16x4(pa1), as_s16x4(v1), O[qt][ct]);
      }
    }
  }
}

// normalize by 1/l and store O bf16 -> [512][64] swizzled tile
__device__ __forceinline__ void write_O(char* buf, const f32x4 (&O)[2][4], const float (&lsum)[2],
                                        int wave, int lane) {
  int g = lane >> 4, q15 = lane & 15;
#pragma unroll
  for (int qt = 0; qt < 2; ++qt) {
    float inv = 1.f / lsum[qt];
    float invr[4];
#pragma unroll
    for (int rr = 0; rr < 4; ++rr) invr[rr] = __shfl(inv, 4*g + rr);
#pragma unroll
    for (int ct = 0; ct < 4; ++ct)
#pragma unroll
      for (int rr = 0; rr < 4; ++rr)
        *(short*)(buf + swz128(wave*32 + qt*16 + 4*g + rr, 2*(ct*16 + q15))) =
            (short)b16rne(O[qt][ct][rr] * invr[rr]);
  }
}

// plain epilogue: out = xres + coef*G (pair-split, 32 ch per thread)
__device__ __forceinline__ void epi32(const char* bufG, const float* __restrict__ xres,
                                      const float* __restrict__ coef, float* __restrict__ outp,
                                      int base, int pix, int half) {
  const int c0 = half*32;
#pragma unroll
  for (int i2 = 0; i2 < 4; ++i2) {
    u32x4 gv = *(const u32x4*)(bufG + swz128(pix, half*64 + i2*16));
#pragma unroll
    for (int e = 0; e < 4; ++e) {
      int i = i2*8 + e*2;
      int idx = base + (c0+i)*HW_ + pix;
      outp[idx]       = xres[idx]       + coef[c0+i]   * bflo(gv[e]);
      outp[idx + HW_] = xres[idx + HW_] + coef[c0+i+1] * bfhi(gv[e]);
    }
  }
}

// fused epilogue + LayerNorm of the residual input (reads xres once)
__device__ __forceinline__ void epi_ln(const char* bufG, const float* __restrict__ xres,
                                       const float* __restrict__ coef, float* __restrict__ outp,
                                       const float* __restrict__ w, const float* __restrict__ bb,
                                       char* bufLN, int base, int pix, int half,
                                       float* redS, float* redSS) {
  const int c0 = half*32;
  float xv[32], s = 0.f, ss = 0.f;
#pragma unroll
  for (int i2 = 0; i2 < 4; ++i2) {
    u32x4 gv = *(const u32x4*)(bufG + swz128(pix, half*64 + i2*16));
#pragma unroll
    for (int e = 0; e < 4; ++e) {
      int i = i2*8 + e*2;
      int idx = base + (c0+i)*HW_ + pix;
      float x0 = xres[idx], x1 = xres[idx + HW_];
      xv[i] = x0; xv[i+1] = x1;
      s += x0 + x1; ss = fmaf(x0,x0,ss); ss = fmaf(x1,x1,ss);
      outp[idx]       = x0 + coef[c0+i]   * bflo(gv[e]);
      outp[idx + HW_] = x1 + coef[c0+i+1] * bfhi(gv[e]);
    }
  }
  redS[half*512 + pix] = s; redSS[half*512 + pix] = ss;
  __syncthreads();
  float st  = redS[pix]  + redS[512 + pix];
  float sst = redSS[pix] + redSS[512 + pix];
  float mu = st * 0.015625f;
  float rs = rsqrtf(fmaxf(sst * 0.015625f - mu*mu, 0.f) + 1e-6f);
#pragma unroll
  for (int i2 = 0; i2 < 4; ++i2) {
    u32x4 u;
#pragma unroll
    for (int e = 0; e < 4; ++e) {
      int i = i2*8 + e*2;
      float y0 = (xv[i  ]-mu)*rs*w[c0+i  ] + bb[c0+i  ];
      float y1 = (xv[i+1]-mu)*rs*w[c0+i+1] + bb[c0+i+1];
      u[e] = pack2(y0, y1);
    }
    *(u32x4*)(bufLN + swz128(pix, half*64 + i2*16)) = u;
  }
}

__global__ __launch_bounds__(1024, 4)   // 4 waves/EU min (exactly 1 block/CU) -> 128 VGPR budget
void scam_mfma(const float* __restrict__ xl, const float* __restrict__ xr,
               const float* __restrict__ nlw, const float* __restrict__ nlb,
               const float* __restrict__ nrw, const float* __restrict__ nrb,
               const float* __restrict__ l1w, const float* __restrict__ l1b,
               const float* __restrict__ r1w, const float* __restrict__ r1b,
               const float* __restrict__ l2w, const float* __restrict__ l2b,
               const float* __restrict__ r2w, const float* __restrict__ r2b,
               const float* __restrict__ beta, const float* __restrict__ gamma,
               float* __restrict__ out) {
  __shared__ __align__(16) char bufA[65536];
  __shared__ __align__(16) char bufB[65536];
  __shared__ __align__(16) char bufW[8192];
  __shared__ float redS[1024];
  __shared__ float redSS[1024];

  const int t = threadIdx.x, lane = t & 63, wave = t >> 6;
  const int pix = t & 511, half = t >> 9;
  const int r = blockIdx.x, b = r >> 7, h = r & 127;
  const int base = b*CHW_ + h*512;

  // P0: W1l -> W ; LN(x_l) -> A
  if (t < 512) stageW(l1w, bufW, t);
  ln32(xl, base, pix, half, nlw, nlb, bufA, redS, redSS);
  __syncthreads();
  // P1: Q_l = LN(x_l)@W1l^T + b1l -> B
  proj64(bufA, bufW, l1b, bufB, wave, lane);
  __syncthreads();
  // P2: qfL <- B ; W1r -> W ; LN(x_r) -> A
  s16x8 qfL[2][2];
  extract_q(bufB, wave, lane, qfL);
  if (t < 512) stageW(r1w, bufW, t);
  ln32(xr, base, pix, half, nrw, nrb, bufA, redS, redSS);
  __syncthreads();
  // P3: Q_r -> B
  proj64(bufA, bufW, r1b, bufB, wave, lane);
  __syncthreads();
  // P4: V^T = x_r -> A ; W2r -> W
  stageV(xr, base, bufA, t);
  if (t < 512) stageW(r2w, bufW, t);
  __syncthreads();
  // A1: F_r2l = Attn(Q_l, Q_r, x_r); then harvest qfR (Q_r tile still in B)
  f32x4 O[2][4]; float lsum[2];
  flash_pass(bufB, bufA, qfL, O, lsum, lane);
  s16x8 qfR[2][2];
  extract_q(bufB, wave, lane, qfR);
  __syncthreads();
  // P5: O1 -> A
  write_O(bufA, O, lsum, wave, lane);
  __syncthreads();
  // E1a: G1 = O1@W2r^T + b2r -> B
  proj64(bufA, bufW, r2b, bufB, wave, lane);
  __syncthreads();
  // E1b: out_l = x_l + beta*G1 (fused with LN(x_l) -> A) ; W1l -> W
  if (t < 512) stageW(l1w, bufW, t);
  epi_ln(bufB, xl, beta, out, nlw, nlb, bufA, base, pix, half, redS, redSS);
  __syncthreads();
  // P7: Q_l -> B
  proj64(bufA, bufW, l1b, bufB, wave, lane);
  __syncthreads();
  // P8: V^T = x_l -> A ; W2l -> W
  stageV(xl, base, bufA, t);
  if (t < 512) stageW(l2w, bufW, t);
  __syncthreads();
  // A2: F_l2r = Attn(Q_r, Q_l, x_l)
  flash_pass(bufB, bufA, qfR, O, lsum, lane);
  __syncthreads();
  // P9: O2 -> A
  write_O(bufA, O, lsum, wave, lane);
  __syncthreads();
  // E2a: G2 = O2@W2l^T + b2l -> B
  proj64(bufA, bufW, l2b, bufB, wave, lane);
  __syncthreads();
  // E2b: out_r = x_r + gamma*G2
  epi32(bufB, xr, gamma, out + OUTR_, base, pix, half);
}

extern "C" void kernel_launch(void* const* d_in, const int* in_sizes, int n_in,
                              void* d_out, int out_size, void* d_ws, size_t ws_size,
                              hipStream_t stream) {
  (void)in_sizes; (void)n_in; (void)d_ws; (void)ws_size; (void)out_size;
  scam_mfma<<<dim3(512), dim3(1024), 0, stream>>>(
      (const float*)d_in[0],  (const float*)d_in[1],
      (const float*)d_in[2],  (const float*)d_in[3],
      (const float*)d_in[4],  (const float*)d_in[5],
      (const float*)d_in[6],  (const float*)d_in[7],
      (const float*)d_in[8],  (const float*)d_in[9],
      (const float*)d_in[10], (const float*)d_in[11],
      (const float*)d_in[12], (const float*)d_in[13],
      (const float*)d_in[14], (const float*)d_in[15],
      (float*)d_out);
}